// Round 1
// baseline (5026.492 us; speedup 1.0000x reference)
//
#include <hip/hip_runtime.h>

#define NN 100000
#define NE 3200000
#define FIN 128
#define HID 32
#define MH  64
#define NC  10
#define NG  64

// deg init to 1.0 (self-loop weight); zero pooled sums+counts (2112 floats)
__global__ void init_misc(float* __restrict__ deg, float* __restrict__ sc) {
    int i = blockIdx.x * 256 + threadIdx.x;
    if (i < NN) deg[i] = 1.0f;
    if (i < NG * HID + NG) sc[i] = 0.0f;
}

__global__ void accum_deg(const int* __restrict__ ei, const float* __restrict__ ew,
                          float* __restrict__ deg) {
    int e = blockIdx.x * 256 + threadIdx.x;
    if (e < NE) atomicAdd(&deg[ei[NE + e]], ew[e]);
}

__global__ void rsqrt_k(float* __restrict__ deg) {
    int i = blockIdx.x * 256 + threadIdx.x;
    if (i < NN) deg[i] = rsqrtf(deg[i]);   // deg >= 1 always (self-loop)
}

__global__ void norm_k(const int* __restrict__ ei, const float* __restrict__ ew,
                       const float* __restrict__ dinv, float* __restrict__ nrm) {
    int e = blockIdx.x * 256 + threadIdx.x;
    if (e < NE) nrm[e] = dinv[ei[e]] * ew[e] * dinv[ei[NE + e]];
}

// tmp = act(in) @ W   and   outi = bias + dinv^2 * tmp   (self-loop + bias pre-init
// of the scatter target, so no separate zero/init pass is needed)
template <int IN_DIM, bool RELU_IN>
__global__ void linear_k(const float* __restrict__ in, const float* __restrict__ W,
                         const float* __restrict__ bias, const float* __restrict__ dinv,
                         float* __restrict__ tmp, float* __restrict__ outi) {
    __shared__ float Wl[IN_DIM * HID];
    int tid = threadIdx.x;  // 256 = 8 rows x 32 cols
    for (int idx = tid; idx < IN_DIM * HID; idx += 256) Wl[idx] = W[idx];
    __syncthreads();
    int row = blockIdx.x * 8 + (tid >> 5);
    if (row >= NN) return;
    int k = tid & 31;
    const float* xr = in + (size_t)row * IN_DIM;
    float acc = 0.f;
#pragma unroll 8
    for (int j = 0; j < IN_DIM; ++j) {
        float v = xr[j];
        if (RELU_IN) v = fmaxf(v, 0.f);
        acc = fmaf(v, Wl[j * HID + k], acc);
    }
    int idx = row * HID + k;
    tmp[idx] = acc;
    float di = dinv[row];
    outi[idx] = bias[k] + di * di * acc;
}

// one edge handled by 8 threads (float4 each): gather tmp[row], atomic-add into out[col]
__global__ void scatter_edges(const float4* __restrict__ tmp4, const int* __restrict__ ei,
                              const float* __restrict__ nrm, float* __restrict__ out) {
    int t = blockIdx.x * 256 + threadIdx.x;  // < NE*8 exactly
    int e = t >> 3;
    int kq = t & 7;
    int r = ei[e];
    int c = ei[NE + e];
    float nm = nrm[e];
    float4 v = tmp4[r * 8 + kq];
    float* dst = out + c * HID + kq * 4;
    atomicAdd(dst + 0, nm * v.x);
    atomicAdd(dst + 1, nm * v.y);
    atomicAdd(dst + 2, nm * v.z);
    atomicAdd(dst + 3, nm * v.w);
}

__global__ void pool_k(const float* __restrict__ h, const int* __restrict__ batch,
                       float* __restrict__ sums, float* __restrict__ counts) {
    int idx = blockIdx.x * 256 + threadIdx.x;  // < NN*HID exactly
    int i = idx >> 5, k = idx & 31;
    int g = batch[i];
    atomicAdd(&sums[g * HID + k], h[idx]);
    if (k == 0) atomicAdd(&counts[g], 1.0f);
}

// whole MLP in one block (tiny: 64x32 -> 64x64 -> 64x64 -> 64x10)
__global__ void mlp_k(const float* __restrict__ sums, const float* __restrict__ counts,
                      const float* __restrict__ Wm0, const float* __restrict__ bm0,
                      const float* __restrict__ Wm1, const float* __restrict__ bm1,
                      const float* __restrict__ Wout, const float* __restrict__ bout,
                      float* __restrict__ out) {
    __shared__ float g0[NG * HID];
    __shared__ float g1[NG * MH];
    __shared__ float g2[NG * MH];
    int tid = threadIdx.x;
    for (int idx = tid; idx < NG * HID; idx += 256) {
        int g = idx / HID;
        g0[idx] = sums[idx] / fmaxf(counts[g], 1.0f);
    }
    __syncthreads();
    for (int idx = tid; idx < NG * MH; idx += 256) {
        int g = idx / MH, k = idx % MH;
        float acc = bm0[k];
        for (int j = 0; j < HID; ++j) acc = fmaf(g0[g * HID + j], Wm0[j * MH + k], acc);
        g1[idx] = fmaxf(acc, 0.f);
    }
    __syncthreads();
    for (int idx = tid; idx < NG * MH; idx += 256) {
        int g = idx / MH, k = idx % MH;
        float acc = bm1[k];
        for (int j = 0; j < MH; ++j) acc = fmaf(g1[g * MH + j], Wm1[j * MH + k], acc);
        g2[idx] = fmaxf(acc, 0.f);
    }
    __syncthreads();
    for (int idx = tid; idx < NG * NC; idx += 256) {
        int g = idx / NC, k = idx % NC;
        float acc = bout[k];
        for (int j = 0; j < MH; ++j) acc = fmaf(g2[g * MH + j], Wout[j * NC + k], acc);
        out[idx] = acc;
    }
}

extern "C" void kernel_launch(void* const* d_in, const int* in_sizes, int n_in,
                              void* d_out, int out_size, void* d_ws, size_t ws_size,
                              hipStream_t stream) {
    const float* x    = (const float*)d_in[0];
    const int*   ei   = (const int*)d_in[1];
    const float* ew   = (const float*)d_in[2];
    const int*   batch= (const int*)d_in[3];
    const float* W1   = (const float*)d_in[4];
    const float* b1   = (const float*)d_in[5];
    const float* W2   = (const float*)d_in[6];
    const float* b2   = (const float*)d_in[7];
    const float* W3   = (const float*)d_in[8];
    const float* b3   = (const float*)d_in[9];
    const float* Wm0  = (const float*)d_in[10];
    const float* bm0  = (const float*)d_in[11];
    const float* Wm1  = (const float*)d_in[12];
    const float* bm1  = (const float*)d_in[13];
    const float* Wout = (const float*)d_in[14];
    const float* bout = (const float*)d_in[15];
    float* out = (float*)d_out;

    // workspace layout (floats): norm[NE] | deg/dinv[NN] | tmp[NN*32] | hA | hB | sums[2048] | counts[64]
    float* nrm   = (float*)d_ws;
    float* deg   = nrm + NE;
    float* tmp   = deg + NN;
    float* hA    = tmp + (size_t)NN * HID;
    float* hB    = hA + (size_t)NN * HID;
    float* sums  = hB + (size_t)NN * HID;
    float* counts= sums + NG * HID;

    dim3 blk(256);
    init_misc<<<391, blk, 0, stream>>>(deg, sums);
    accum_deg<<<12500, blk, 0, stream>>>(ei, ew, deg);
    rsqrt_k<<<391, blk, 0, stream>>>(deg);                 // deg -> dinv in place
    norm_k<<<12500, blk, 0, stream>>>(ei, ew, deg, nrm);

    // layer 1: tmp = x@W1 ; hA = b1 + dinv^2*tmp ; hA += scatter(norm*tmp[row] -> col)
    linear_k<FIN, false><<<12500, blk, 0, stream>>>(x, W1, b1, deg, tmp, hA);
    scatter_edges<<<100000, blk, 0, stream>>>((const float4*)tmp, ei, nrm, hA);
    // layer 2 (relu on input of linear)
    linear_k<HID, true><<<12500, blk, 0, stream>>>(hA, W2, b2, deg, tmp, hB);
    scatter_edges<<<100000, blk, 0, stream>>>((const float4*)tmp, ei, nrm, hB);
    // layer 3 (no relu on output; pool reads raw)
    linear_k<HID, true><<<12500, blk, 0, stream>>>(hB, W3, b3, deg, tmp, hA);
    scatter_edges<<<100000, blk, 0, stream>>>((const float4*)tmp, ei, nrm, hA);

    pool_k<<<12500, blk, 0, stream>>>(hA, batch, sums, counts);
    mlp_k<<<1, blk, 0, stream>>>(sums, counts, Wm0, bm0, Wm1, bm1, Wout, bout, out);
}

// Round 2
// 1209.278 us; speedup vs baseline: 4.1566x; 4.1566x over previous
//
#include <hip/hip_runtime.h>

#define NN 100000
#define NE 3200000
#define FIN 128
#define HID 32
#define MH  64
#define NC  10
#define NG  64

// deg=1.0 (self-loop), cnt=0, pooled sums+counts=0
__global__ void init_misc(float* __restrict__ deg, int* __restrict__ cnt,
                          float* __restrict__ sc) {
    int i = blockIdx.x * 256 + threadIdx.x;
    if (i < NN) { deg[i] = 1.0f; cnt[i] = 0; }
    if (i < NG * HID + NG) sc[i] = 0.0f;
}

// weighted degree + in-degree count histogram, keyed by destination (col)
__global__ void hist_deg(const int* __restrict__ ei, const float* __restrict__ ew,
                         float* __restrict__ deg, int* __restrict__ cnt) {
    int e = blockIdx.x * 256 + threadIdx.x;
    if (e < NE) {
        int c = ei[NE + e];
        atomicAdd(&deg[c], ew[e]);
        atomicAdd(&cnt[c], 1);
    }
}

__global__ void rsqrt_k(float* __restrict__ deg) {
    int i = blockIdx.x * 256 + threadIdx.x;
    if (i < NN) deg[i] = rsqrtf(deg[i]);   // deg >= 1 (self-loop) -> dinv in place
}

// ---- exclusive scan of cnt[NN] -> rowptr (start offsets), 1024 elems/block ----
__global__ void scan_block(const int* __restrict__ cnt, int* __restrict__ rowptr,
                           int* __restrict__ bsum) {
    __shared__ int lds[256];
    int tid = threadIdx.x;
    int base = blockIdx.x * 1024 + tid * 4;
    int v0 = 0, v1 = 0, v2 = 0, v3 = 0;
    if (base + 0 < NN) v0 = cnt[base + 0];
    if (base + 1 < NN) v1 = cnt[base + 1];
    if (base + 2 < NN) v2 = cnt[base + 2];
    if (base + 3 < NN) v3 = cnt[base + 3];
    int s = v0 + v1 + v2 + v3;
    lds[tid] = s;
    __syncthreads();
    for (int off = 1; off < 256; off <<= 1) {
        int val = (tid >= off) ? lds[tid - off] : 0;
        __syncthreads();
        lds[tid] += val;
        __syncthreads();
    }
    int excl = lds[tid] - s;
    if (tid == 255) bsum[blockIdx.x] = lds[255];
    if (base + 0 < NN) rowptr[base + 0] = excl;
    if (base + 1 < NN) rowptr[base + 1] = excl + v0;
    if (base + 2 < NN) rowptr[base + 2] = excl + v0 + v1;
    if (base + 3 < NN) rowptr[base + 3] = excl + v0 + v1 + v2;
}

__global__ void scan_top(int* __restrict__ bsum, int nb) {
    if (threadIdx.x == 0) {
        int acc = 0;
        for (int i = 0; i < nb; ++i) { int v = bsum[i]; bsum[i] = acc; acc += v; }
    }
}

__global__ void scan_add(int* __restrict__ rowptr, const int* __restrict__ bsum) {
    int i = blockIdx.x * 256 + threadIdx.x;
    if (i < NN) rowptr[i] += bsum[i >> 10];
}

// allocate position via atomicAdd on rowptr (start cursors); afterwards
// rowptr[c] == end offset of node c (start of c = rowptr[c-1], 0 for c==0).
// stores (src_row, norm) as int2 sorted-by-destination.
__global__ void reorder(const int* __restrict__ ei, const float* __restrict__ ew,
                        const float* __restrict__ dinv, int* __restrict__ rowptr,
                        int2* __restrict__ srn) {
    int e = blockIdx.x * 256 + threadIdx.x;
    if (e < NE) {
        int r = ei[e], c = ei[NE + e];
        float nm = dinv[r] * ew[e] * dinv[c];
        int p = atomicAdd(&rowptr[c], 1);
        srn[p] = make_int2(r, __float_as_int(nm));
    }
}

// tmp = act(in) @ W ; outi = bias + dinv^2 * tmp (self-loop + bias pre-init)
template <int IN_DIM, bool RELU_IN>
__global__ void linear_k(const float* __restrict__ in, const float* __restrict__ W,
                         const float* __restrict__ bias, const float* __restrict__ dinv,
                         float* __restrict__ tmp, float* __restrict__ outi) {
    __shared__ float Wl[IN_DIM * HID];
    int tid = threadIdx.x;  // 256 = 8 rows x 32 cols
    for (int idx = tid; idx < IN_DIM * HID; idx += 256) Wl[idx] = W[idx];
    __syncthreads();
    int row = blockIdx.x * 8 + (tid >> 5);
    if (row >= NN) return;
    int k = tid & 31;
    const float* xr = in + (size_t)row * IN_DIM;
    float acc = 0.f;
#pragma unroll 8
    for (int j = 0; j < IN_DIM; ++j) {
        float v = xr[j];
        if (RELU_IN) v = fmaxf(v, 0.f);
        acc = fmaf(v, Wl[j * HID + k], acc);
    }
    int idx = row * HID + k;
    tmp[idx] = acc;
    float di = dinv[row];
    outi[idx] = bias[k] + di * di * acc;
}

// one wave per destination node: 64 lanes = 32 features x 2 edges.
// gathers tmp rows (L2/L3-resident), register-accumulates, no atomics.
__global__ void aggregate(const int2* __restrict__ srn, const int* __restrict__ rowptr,
                          const float* __restrict__ tmp, float* __restrict__ h) {
    int wid = (blockIdx.x * 256 + threadIdx.x) >> 6;  // node id
    if (wid >= NN) return;
    int lane = threadIdx.x & 63;
    int eo = lane >> 5, k = lane & 31;
    int end = rowptr[wid];
    int start = (wid == 0) ? 0 : rowptr[wid - 1];
    float acc = 0.f;
    for (int e = start + eo; e < end; e += 2) {
        int2 p = srn[e];
        acc = fmaf(__int_as_float(p.y), tmp[(size_t)p.x * HID + k], acc);
    }
    acc += __shfl_xor(acc, 32, 64);
    if (eo == 0) {
        int idx = wid * HID + k;
        h[idx] += acc;  // h pre-initialized with bias + dinv^2*tmp (single writer)
    }
}

// sorted-batch run-length pooling: ~32x fewer atomics than per-element
__global__ void pool_k(const float* __restrict__ h, const int* __restrict__ batch,
                       float* __restrict__ sums, float* __restrict__ counts) {
    int t = blockIdx.x * 256 + threadIdx.x;
    int chunk = t >> 5, k = t & 31;
    int n0 = chunk * 32;
    if (n0 >= NN) return;
    int n1 = min(n0 + 32, NN);
    int g = batch[n0];
    float acc = 0.f, cacc = 0.f;
    for (int i = n0; i < n1; ++i) {
        int gi = batch[i];
        if (gi != g) {
            atomicAdd(&sums[g * HID + k], acc);
            if (k == 0) atomicAdd(&counts[g], cacc);
            g = gi; acc = 0.f; cacc = 0.f;
        }
        acc += h[(size_t)i * HID + k];
        cacc += 1.f;
    }
    atomicAdd(&sums[g * HID + k], acc);
    if (k == 0) atomicAdd(&counts[g], cacc);
}

// whole MLP in one block (64x32 -> 64x64 -> 64x64 -> 64x10)
__global__ void mlp_k(const float* __restrict__ sums, const float* __restrict__ counts,
                      const float* __restrict__ Wm0, const float* __restrict__ bm0,
                      const float* __restrict__ Wm1, const float* __restrict__ bm1,
                      const float* __restrict__ Wout, const float* __restrict__ bout,
                      float* __restrict__ out) {
    __shared__ float g0[NG * HID];
    __shared__ float g1[NG * MH];
    __shared__ float g2[NG * MH];
    int tid = threadIdx.x;
    for (int idx = tid; idx < NG * HID; idx += 256) {
        int g = idx / HID;
        g0[idx] = sums[idx] / fmaxf(counts[g], 1.0f);
    }
    __syncthreads();
    for (int idx = tid; idx < NG * MH; idx += 256) {
        int g = idx / MH, k = idx % MH;
        float acc = bm0[k];
        for (int j = 0; j < HID; ++j) acc = fmaf(g0[g * HID + j], Wm0[j * MH + k], acc);
        g1[idx] = fmaxf(acc, 0.f);
    }
    __syncthreads();
    for (int idx = tid; idx < NG * MH; idx += 256) {
        int g = idx / MH, k = idx % MH;
        float acc = bm1[k];
        for (int j = 0; j < MH; ++j) acc = fmaf(g1[g * MH + j], Wm1[j * MH + k], acc);
        g2[idx] = fmaxf(acc, 0.f);
    }
    __syncthreads();
    for (int idx = tid; idx < NG * NC; idx += 256) {
        int g = idx / NC, k = idx % NC;
        float acc = bout[k];
        for (int j = 0; j < MH; ++j) acc = fmaf(g2[g * MH + j], Wout[j * NC + k], acc);
        out[idx] = acc;
    }
}

extern "C" void kernel_launch(void* const* d_in, const int* in_sizes, int n_in,
                              void* d_out, int out_size, void* d_ws, size_t ws_size,
                              hipStream_t stream) {
    const float* x    = (const float*)d_in[0];
    const int*   ei   = (const int*)d_in[1];
    const float* ew   = (const float*)d_in[2];
    const int*   batch= (const int*)d_in[3];
    const float* W1   = (const float*)d_in[4];
    const float* b1   = (const float*)d_in[5];
    const float* W2   = (const float*)d_in[6];
    const float* b2   = (const float*)d_in[7];
    const float* W3   = (const float*)d_in[8];
    const float* b3   = (const float*)d_in[9];
    const float* Wm0  = (const float*)d_in[10];
    const float* bm0  = (const float*)d_in[11];
    const float* Wm1  = (const float*)d_in[12];
    const float* bm1  = (const float*)d_in[13];
    const float* Wout = (const float*)d_in[14];
    const float* bout = (const float*)d_in[15];
    float* out = (float*)d_out;

    // workspace layout
    char* p = (char*)d_ws;
    int2*  srn    = (int2*)p;            p += sizeof(int2) * (size_t)NE;   // 25.6 MB
    int*   cnt    = (int*)p;             p += sizeof(int) * NN;
    int*   rowptr = (int*)p;             p += sizeof(int) * NN;
    int*   bsum   = (int*)p;             p += sizeof(int) * 128;
    float* deg    = (float*)p;           p += sizeof(float) * NN;
    float* tmp    = (float*)p;           p += sizeof(float) * (size_t)NN * HID;
    float* hA     = (float*)p;           p += sizeof(float) * (size_t)NN * HID;
    float* hB     = (float*)p;           p += sizeof(float) * (size_t)NN * HID;
    float* sums   = (float*)p;           p += sizeof(float) * NG * HID;
    float* counts = (float*)p;

    dim3 blk(256);
    const int NB_SCAN = (NN + 1023) / 1024;  // 98

    init_misc<<<391, blk, 0, stream>>>(deg, cnt, sums);
    hist_deg<<<12500, blk, 0, stream>>>(ei, ew, deg, cnt);
    rsqrt_k<<<391, blk, 0, stream>>>(deg);  // deg -> dinv
    scan_block<<<NB_SCAN, blk, 0, stream>>>(cnt, rowptr, bsum);
    scan_top<<<1, 64, 0, stream>>>(bsum, NB_SCAN);
    scan_add<<<391, blk, 0, stream>>>(rowptr, bsum);
    reorder<<<12500, blk, 0, stream>>>(ei, ew, deg, rowptr, srn);

    // layer 1
    linear_k<FIN, false><<<12500, blk, 0, stream>>>(x, W1, b1, deg, tmp, hA);
    aggregate<<<25000, blk, 0, stream>>>(srn, rowptr, tmp, hA);
    // layer 2
    linear_k<HID, true><<<12500, blk, 0, stream>>>(hA, W2, b2, deg, tmp, hB);
    aggregate<<<25000, blk, 0, stream>>>(srn, rowptr, tmp, hB);
    // layer 3
    linear_k<HID, true><<<12500, blk, 0, stream>>>(hB, W3, b3, deg, tmp, hA);
    aggregate<<<25000, blk, 0, stream>>>(srn, rowptr, tmp, hA);

    pool_k<<<391, blk, 0, stream>>>(hA, batch, sums, counts);
    mlp_k<<<1, blk, 0, stream>>>(sums, counts, Wm0, bm0, Wm1, bm1, Wout, bout, out);
}

// Round 3
// 868.182 us; speedup vs baseline: 5.7897x; 1.3929x over previous
//
#include <hip/hip_runtime.h>

#define NN 100000
#define NE 3200000
#define FIN 128
#define HID 32
#define MH  64
#define NC  10
#define NG  64
#define NBKT 782           // ceil(NN/128) buckets of 128 dest nodes
#define NBLK 256           // edge-pass blocks
#define EPB  (NE / NBLK)   // 12500 edges per block
#define SCANL (NBKT * NBLK)

__global__ void init_misc(float* __restrict__ sc) {
    int i = blockIdx.x * 256 + threadIdx.x;
    if (i < NG * HID + NG) sc[i] = 0.0f;
}

// per-block LDS histogram over 782 dest-buckets; no global atomics
__global__ void hist_bkt(const int* __restrict__ ei, int* __restrict__ cnt2) {
    __shared__ int h[NBKT];
    int tid = threadIdx.x, blk = blockIdx.x;
    for (int b = tid; b < NBKT; b += 256) h[b] = 0;
    __syncthreads();
    int base = blk * EPB;
    for (int i = tid; i < EPB; i += 256)
        atomicAdd(&h[ei[NE + base + i] >> 7], 1);
    __syncthreads();
    for (int b = tid; b < NBKT; b += 256) cnt2[b * NBLK + blk] = h[b];
}

// ---- generic exclusive scan (1024 elems/block) ----
__global__ void scan_block(const int* __restrict__ in, int* __restrict__ out,
                           int* __restrict__ bsum, int n) {
    __shared__ int lds[256];
    int tid = threadIdx.x;
    int base = blockIdx.x * 1024 + tid * 4;
    int v0 = 0, v1 = 0, v2 = 0, v3 = 0;
    if (base + 0 < n) v0 = in[base + 0];
    if (base + 1 < n) v1 = in[base + 1];
    if (base + 2 < n) v2 = in[base + 2];
    if (base + 3 < n) v3 = in[base + 3];
    int s = v0 + v1 + v2 + v3;
    lds[tid] = s;
    __syncthreads();
    for (int off = 1; off < 256; off <<= 1) {
        int val = (tid >= off) ? lds[tid - off] : 0;
        __syncthreads();
        lds[tid] += val;
        __syncthreads();
    }
    int excl = lds[tid] - s;
    if (tid == 255) bsum[blockIdx.x] = lds[255];
    if (base + 0 < n) out[base + 0] = excl;
    if (base + 1 < n) out[base + 1] = excl + v0;
    if (base + 2 < n) out[base + 2] = excl + v0 + v1;
    if (base + 3 < n) out[base + 3] = excl + v0 + v1 + v2;
}

__global__ void scan_top(int* __restrict__ bsum, int nb) {
    if (threadIdx.x == 0) {
        int acc = 0;
        for (int i = 0; i < nb; ++i) { int v = bsum[i]; bsum[i] = acc; acc += v; }
    }
}

__global__ void scan_add(int* __restrict__ data, const int* __restrict__ bsum, int n) {
    int i = blockIdx.x * 256 + threadIdx.x;
    if (i < n) data[i] += bsum[i >> 10];
}

// scatter edges into dest-buckets; LDS cursors (no global atomics); each
// (block,bucket) run is contiguous in the output
__global__ void scatter_bkt(const int* __restrict__ ei, const float* __restrict__ ew,
                            const int* __restrict__ scanned,
                            int2* __restrict__ tre, int* __restrict__ tc) {
    __shared__ int cur[NBKT];
    int tid = threadIdx.x, blk = blockIdx.x;
    for (int b = tid; b < NBKT; b += 256) cur[b] = scanned[b * NBLK + blk];
    __syncthreads();
    int base = blk * EPB;
    for (int i = tid; i < EPB; i += 256) {
        int e = base + i;
        int c = ei[NE + e];
        int pos = atomicAdd(&cur[c >> 7], 1);
        tre[pos] = make_int2(ei[e], __float_as_int(ew[e]));
        tc[pos] = c;
    }
}

// one block per bucket: 128-bin count+scan in LDS, emit sorted (src, ew),
// rowptr (end offsets), and dinv = rsqrt(1 + weighted_indeg)
__global__ void bucket_sort(const int2* __restrict__ tre, const int* __restrict__ tc,
                            const int* __restrict__ scanned,
                            int2* __restrict__ srn, int* __restrict__ rowptr,
                            float* __restrict__ dinv) {
    __shared__ int h[128];
    __shared__ float dw[128];
    __shared__ int sc[128];
    __shared__ int cur[128];
    int b = blockIdx.x, tid = threadIdx.x;
    int base = scanned[b * NBLK];
    int end = (b == NBKT - 1) ? NE : scanned[(b + 1) * NBLK];
    int n = end - base;
    if (tid < 128) { h[tid] = 0; dw[tid] = 0.f; }
    __syncthreads();
    for (int i = tid; i < n; i += 256) {
        int key = tc[base + i] & 127;
        atomicAdd(&h[key], 1);
        atomicAdd(&dw[key], __int_as_float(tre[base + i].y));
    }
    __syncthreads();
    if (tid < 128) sc[tid] = h[tid];
    __syncthreads();
    for (int off = 1; off < 128; off <<= 1) {
        int v = (tid < 128 && tid >= off) ? sc[tid - off] : 0;
        __syncthreads();
        if (tid < 128) sc[tid] += v;
        __syncthreads();
    }
    if (tid < 128) {
        int node = b * 128 + tid;
        if (node < NN) {
            rowptr[node] = base + sc[tid];               // end offset
            dinv[node] = rsqrtf(1.0f + dw[tid]);         // self-loop included
        }
        cur[tid] = base + sc[tid] - h[tid];              // start cursor
    }
    __syncthreads();
    for (int i = tid; i < n; i += 256) {
        int key = tc[base + i] & 127;
        int pos = atomicAdd(&cur[key], 1);
        srn[pos] = tre[base + i];
    }
}

// srn.y: ew -> ew * dinv[src]
__global__ void finalize_wn(int2* __restrict__ srn, const float* __restrict__ dinv) {
    int e = blockIdx.x * 256 + threadIdx.x;
    if (e < NE) {
        int2 p = srn[e];
        srn[e] = make_int2(p.x, __float_as_int(__int_as_float(p.y) * dinv[p.x]));
    }
}

// tmp = act(in) @ W ; outi = bias + dinv^2 * tmp (self-loop + bias pre-init)
template <int IN_DIM, bool RELU_IN>
__global__ void linear_k(const float* __restrict__ in, const float* __restrict__ W,
                         const float* __restrict__ bias, const float* __restrict__ dinv,
                         float* __restrict__ tmp, float* __restrict__ outi) {
    __shared__ float Wl[IN_DIM * HID];
    int tid = threadIdx.x;  // 256 = 8 rows x 32 cols
    for (int idx = tid; idx < IN_DIM * HID; idx += 256) Wl[idx] = W[idx];
    __syncthreads();
    int row = blockIdx.x * 8 + (tid >> 5);
    if (row >= NN) return;
    int k = tid & 31;
    const float* xr = in + (size_t)row * IN_DIM;
    float acc = 0.f;
#pragma unroll 8
    for (int j = 0; j < IN_DIM; ++j) {
        float v = xr[j];
        if (RELU_IN) v = fmaxf(v, 0.f);
        acc = fmaf(v, Wl[j * HID + k], acc);
    }
    int idx = row * HID + k;
    tmp[idx] = acc;
    float di = dinv[row];
    outi[idx] = bias[k] + di * di * acc;
}

// one wave per dest node: 64 lanes = 32 feats x 2 edge slots; no atomics.
// h[c] += dinv[c] * sum_e wn_e * tmp[r_e]
__global__ void aggregate(const int2* __restrict__ srn, const int* __restrict__ rowptr,
                          const float* __restrict__ dinv,
                          const float* __restrict__ tmp, float* __restrict__ h) {
    int wid = (blockIdx.x * 256 + threadIdx.x) >> 6;
    if (wid >= NN) return;
    int lane = threadIdx.x & 63;
    int eo = lane >> 5, k = lane & 31;
    int end = rowptr[wid];
    int start = (wid == 0) ? 0 : rowptr[wid - 1];
    float acc = 0.f;
    int e = start + eo;
    int2 p = (e < end) ? srn[e] : make_int2(0, 0);
    while (e < end) {
        int2 curp = p;
        e += 2;
        if (e < end) p = srn[e];
        acc = fmaf(__int_as_float(curp.y), tmp[(size_t)curp.x * HID + k], acc);
    }
    acc += __shfl_xor(acc, 32, 64);
    if (eo == 0) {
        int idx = wid * HID + k;
        h[idx] += dinv[wid] * acc;
    }
}

// sorted-batch run-length pooling
__global__ void pool_k(const float* __restrict__ h, const int* __restrict__ batch,
                       float* __restrict__ sums, float* __restrict__ counts) {
    int t = blockIdx.x * 256 + threadIdx.x;
    int chunk = t >> 5, k = t & 31;
    int n0 = chunk * 32;
    if (n0 >= NN) return;
    int n1 = min(n0 + 32, NN);
    int g = batch[n0];
    float acc = 0.f, cacc = 0.f;
    for (int i = n0; i < n1; ++i) {
        int gi = batch[i];
        if (gi != g) {
            atomicAdd(&sums[g * HID + k], acc);
            if (k == 0) atomicAdd(&counts[g], cacc);
            g = gi; acc = 0.f; cacc = 0.f;
        }
        acc += h[(size_t)i * HID + k];
        cacc += 1.f;
    }
    atomicAdd(&sums[g * HID + k], acc);
    if (k == 0) atomicAdd(&counts[g], cacc);
}

// whole MLP in one block
__global__ void mlp_k(const float* __restrict__ sums, const float* __restrict__ counts,
                      const float* __restrict__ Wm0, const float* __restrict__ bm0,
                      const float* __restrict__ Wm1, const float* __restrict__ bm1,
                      const float* __restrict__ Wout, const float* __restrict__ bout,
                      float* __restrict__ out) {
    __shared__ float g0[NG * HID];
    __shared__ float g1[NG * MH];
    __shared__ float g2[NG * MH];
    int tid = threadIdx.x;
    for (int idx = tid; idx < NG * HID; idx += 256) {
        int g = idx / HID;
        g0[idx] = sums[idx] / fmaxf(counts[g], 1.0f);
    }
    __syncthreads();
    for (int idx = tid; idx < NG * MH; idx += 256) {
        int g = idx / MH, k = idx % MH;
        float acc = bm0[k];
        for (int j = 0; j < HID; ++j) acc = fmaf(g0[g * HID + j], Wm0[j * MH + k], acc);
        g1[idx] = fmaxf(acc, 0.f);
    }
    __syncthreads();
    for (int idx = tid; idx < NG * MH; idx += 256) {
        int g = idx / MH, k = idx % MH;
        float acc = bm1[k];
        for (int j = 0; j < MH; ++j) acc = fmaf(g1[g * MH + j], Wm1[j * MH + k], acc);
        g2[idx] = fmaxf(acc, 0.f);
    }
    __syncthreads();
    for (int idx = tid; idx < NG * NC; idx += 256) {
        int g = idx / NC, k = idx % NC;
        float acc = bout[k];
        for (int j = 0; j < MH; ++j) acc = fmaf(g2[g * MH + j], Wout[j * NC + k], acc);
        out[idx] = acc;
    }
}

extern "C" void kernel_launch(void* const* d_in, const int* in_sizes, int n_in,
                              void* d_out, int out_size, void* d_ws, size_t ws_size,
                              hipStream_t stream) {
    const float* x    = (const float*)d_in[0];
    const int*   ei   = (const int*)d_in[1];
    const float* ew   = (const float*)d_in[2];
    const int*   batch= (const int*)d_in[3];
    const float* W1   = (const float*)d_in[4];
    const float* b1   = (const float*)d_in[5];
    const float* W2   = (const float*)d_in[6];
    const float* b2   = (const float*)d_in[7];
    const float* W3   = (const float*)d_in[8];
    const float* b3   = (const float*)d_in[9];
    const float* Wm0  = (const float*)d_in[10];
    const float* bm0  = (const float*)d_in[11];
    const float* Wm1  = (const float*)d_in[12];
    const float* bm1  = (const float*)d_in[13];
    const float* Wout = (const float*)d_in[14];
    const float* bout = (const float*)d_in[15];
    float* out = (float*)d_out;

    // workspace: srn | sharedRegion(tre+tc <-> tmp+hA+hB, both 38.4MB) | scan bufs | dinv | rowptr | sums
    char* p = (char*)d_ws;
    int2*  srn = (int2*)p;               p += sizeof(int2) * (size_t)NE;      // 25.6 MB
    char*  S   = p;                      p += (8 + 4) * (size_t)NE;           // 38.4 MB shared
    int2*  tre = (int2*)S;
    int*   tc  = (int*)(S + sizeof(int2) * (size_t)NE);
    float* tmp = (float*)S;
    float* hA  = tmp + (size_t)NN * HID;
    float* hB  = hA + (size_t)NN * HID;
    int*   cnt2    = (int*)p;            p += sizeof(int) * SCANL;
    int*   scanned = (int*)p;            p += sizeof(int) * SCANL;
    int*   bsum    = (int*)p;            p += sizeof(int) * 256;
    float* dinv    = (float*)p;          p += sizeof(float) * NN;
    int*   rowptr  = (int*)p;            p += sizeof(int) * NN;
    float* sums    = (float*)p;          p += sizeof(float) * NG * HID;
    float* counts  = (float*)p;

    dim3 blk(256);
    const int NB_SCAN = (SCANL + 1023) / 1024;  // 196

    init_misc<<<9, blk, 0, stream>>>(sums);
    hist_bkt<<<NBLK, blk, 0, stream>>>(ei, cnt2);
    scan_block<<<NB_SCAN, blk, 0, stream>>>(cnt2, scanned, bsum, SCANL);
    scan_top<<<1, 64, 0, stream>>>(bsum, NB_SCAN);
    scan_add<<<(SCANL + 255) / 256, blk, 0, stream>>>(scanned, bsum, SCANL);
    scatter_bkt<<<NBLK, blk, 0, stream>>>(ei, ew, scanned, tre, tc);
    bucket_sort<<<NBKT, blk, 0, stream>>>(tre, tc, scanned, srn, rowptr, dinv);
    finalize_wn<<<(NE + 255) / 256, blk, 0, stream>>>(srn, dinv);

    // layer 1
    linear_k<FIN, false><<<12500, blk, 0, stream>>>(x, W1, b1, dinv, tmp, hA);
    aggregate<<<25000, blk, 0, stream>>>(srn, rowptr, dinv, tmp, hA);
    // layer 2
    linear_k<HID, true><<<12500, blk, 0, stream>>>(hA, W2, b2, dinv, tmp, hB);
    aggregate<<<25000, blk, 0, stream>>>(srn, rowptr, dinv, tmp, hB);
    // layer 3
    linear_k<HID, true><<<12500, blk, 0, stream>>>(hB, W3, b3, dinv, tmp, hA);
    aggregate<<<25000, blk, 0, stream>>>(srn, rowptr, dinv, tmp, hA);

    pool_k<<<391, blk, 0, stream>>>(hA, batch, sums, counts);
    mlp_k<<<1, blk, 0, stream>>>(sums, counts, Wm0, bm0, Wm1, bm1, Wout, bout, out);
}

// Round 4
// 784.897 us; speedup vs baseline: 6.4040x; 1.1061x over previous
//
#include <hip/hip_runtime.h>

#define NN 100000
#define NE 3200000
#define FIN 128
#define HID 32
#define MH  64
#define NC  10
#define NG  64
#define NBKT 782           // ceil(NN/128) buckets of 128 dest nodes
#define NBLK 256           // edge-pass blocks
#define EPB  (NE / NBLK)   // 12500 edges per block
#define SCANL (NBKT * NBLK)
#define SRCMASK 0x1FFFF    // src < 100000 < 2^17

__global__ void init_misc(float* __restrict__ sc) {
    int i = blockIdx.x * 256 + threadIdx.x;
    if (i < NG * HID + NG) sc[i] = 0.0f;
}

// per-block LDS histogram over 782 dest-buckets; no global atomics
__global__ __launch_bounds__(1024)
void hist_bkt(const int* __restrict__ ei, int* __restrict__ cnt2) {
    __shared__ int h[NBKT];
    int tid = threadIdx.x, blk = blockIdx.x;
    for (int b = tid; b < NBKT; b += 1024) h[b] = 0;
    __syncthreads();
    int base = blk * EPB;
    for (int i = tid; i < EPB; i += 1024)
        atomicAdd(&h[ei[NE + base + i] >> 7], 1);
    __syncthreads();
    for (int b = tid; b < NBKT; b += 1024) cnt2[b * NBLK + blk] = h[b];
}

// ---- generic exclusive scan (1024 elems/block) ----
__global__ void scan_block(const int* __restrict__ in, int* __restrict__ out,
                           int* __restrict__ bsum, int n) {
    __shared__ int lds[256];
    int tid = threadIdx.x;
    int base = blockIdx.x * 1024 + tid * 4;
    int v0 = 0, v1 = 0, v2 = 0, v3 = 0;
    if (base + 0 < n) v0 = in[base + 0];
    if (base + 1 < n) v1 = in[base + 1];
    if (base + 2 < n) v2 = in[base + 2];
    if (base + 3 < n) v3 = in[base + 3];
    int s = v0 + v1 + v2 + v3;
    lds[tid] = s;
    __syncthreads();
    for (int off = 1; off < 256; off <<= 1) {
        int val = (tid >= off) ? lds[tid - off] : 0;
        __syncthreads();
        lds[tid] += val;
        __syncthreads();
    }
    int excl = lds[tid] - s;
    if (tid == 255) bsum[blockIdx.x] = lds[255];
    if (base + 0 < n) out[base + 0] = excl;
    if (base + 1 < n) out[base + 1] = excl + v0;
    if (base + 2 < n) out[base + 2] = excl + v0 + v1;
    if (base + 3 < n) out[base + 3] = excl + v0 + v1 + v2;
}

__global__ void scan_top(int* __restrict__ bsum, int nb) {
    if (threadIdx.x == 0) {
        int acc = 0;
        for (int i = 0; i < nb; ++i) { int v = bsum[i]; bsum[i] = acc; acc += v; }
    }
}

__global__ void scan_add(int* __restrict__ data, const int* __restrict__ bsum, int n) {
    int i = blockIdx.x * 256 + threadIdx.x;
    if (i < n) data[i] += bsum[i >> 10];
}

// LDS counting-sort of the block's edges by bucket, then slot-major burst
// writes: consecutive lanes -> consecutive global positions (full-line writes).
// Packs the 7-bit in-bucket key into src's high bits (no tc array).
__global__ __launch_bounds__(1024)
void scatter_bkt(const int* __restrict__ ei, const float* __restrict__ ew,
                 const int* __restrict__ cnt2, const int* __restrict__ scanned,
                 int2* __restrict__ tre) {
    __shared__ int sidx[EPB];      // 50 KB
    __shared__ int hinc[NBKT];
    __shared__ int hexc[NBKT];
    __shared__ int cur[NBKT];
    __shared__ int gbase[NBKT];
    int tid = threadIdx.x, blk = blockIdx.x;
    int myh = 0;
    if (tid < NBKT) {
        myh = cnt2[tid * NBLK + blk];
        gbase[tid] = scanned[tid * NBLK + blk];
        hinc[tid] = myh;
    }
    __syncthreads();
    for (int off = 1; off < NBKT; off <<= 1) {
        int v = (tid < NBKT && tid >= off) ? hinc[tid - off] : 0;
        __syncthreads();
        if (tid < NBKT) hinc[tid] += v;
        __syncthreads();
    }
    if (tid < NBKT) { int ex = hinc[tid] - myh; hexc[tid] = ex; cur[tid] = ex; }
    __syncthreads();
    int base = blk * EPB;
    for (int i = tid; i < EPB; i += 1024) {
        int b = ei[NE + base + i] >> 7;
        int j = atomicAdd(&cur[b], 1);
        sidx[j] = i;
    }
    __syncthreads();
    for (int j = tid; j < EPB; j += 1024) {
        int i = sidx[j];
        int e = base + i;
        int c = ei[NE + e];           // L1/L2 hot (just read in prev pass)
        int b = c >> 7;
        int pos = gbase[b] + (j - hexc[b]);
        tre[pos] = make_int2(ei[e] | ((c & 127) << 17), __float_as_int(ew[e]));
    }
}

// one block per bucket: 128-bin count+scan in LDS, emit node-sorted (src, ew),
// rowptr (end offsets), and dinv = rsqrt(1 + weighted_indeg)
__global__ __launch_bounds__(512)
void bucket_sort(const int2* __restrict__ tre, const int* __restrict__ scanned,
                 int2* __restrict__ srn, int* __restrict__ rowptr,
                 float* __restrict__ dinv) {
    __shared__ int h[128];
    __shared__ float dw[128];
    __shared__ int sc[128];
    __shared__ int cur[128];
    int b = blockIdx.x, tid = threadIdx.x;
    int base = scanned[b * NBLK];
    int end = (b == NBKT - 1) ? NE : scanned[(b + 1) * NBLK];
    int n = end - base;
    if (tid < 128) { h[tid] = 0; dw[tid] = 0.f; }
    __syncthreads();
    for (int i = tid; i < n; i += 512) {
        int2 q = tre[base + i];
        int key = (q.x >> 17) & 127;
        atomicAdd(&h[key], 1);
        atomicAdd(&dw[key], __int_as_float(q.y));
    }
    __syncthreads();
    if (tid < 128) sc[tid] = h[tid];
    __syncthreads();
    for (int off = 1; off < 128; off <<= 1) {
        int v = (tid < 128 && tid >= off) ? sc[tid - off] : 0;
        __syncthreads();
        if (tid < 128) sc[tid] += v;
        __syncthreads();
    }
    if (tid < 128) {
        int node = b * 128 + tid;
        if (node < NN) {
            rowptr[node] = base + sc[tid];               // end offset
            dinv[node] = rsqrtf(1.0f + dw[tid]);         // self-loop included
        }
        cur[tid] = base + sc[tid] - h[tid];              // start cursor
    }
    __syncthreads();
    for (int i = tid; i < n; i += 512) {
        int2 q = tre[base + i];
        int key = (q.x >> 17) & 127;
        int pos = atomicAdd(&cur[key], 1);
        srn[pos] = make_int2(q.x & SRCMASK, q.y);
    }
}

// srn.y: ew -> ew * dinv[src]; 2 edges per thread via int4
__global__ void finalize_wn(int4* __restrict__ srn2, const float* __restrict__ dinv) {
    int t = blockIdx.x * 256 + threadIdx.x;
    if (t < NE / 2) {
        int4 q = srn2[t];
        q.y = __float_as_int(__int_as_float(q.y) * dinv[q.x]);
        q.w = __float_as_int(__int_as_float(q.w) * dinv[q.z]);
        srn2[t] = q;
    }
}

// tmp = act(in) @ W ; outi = bias + dinv^2 * tmp (self-loop + bias pre-init)
template <int IN_DIM, bool RELU_IN>
__global__ void linear_k(const float* __restrict__ in, const float* __restrict__ W,
                         const float* __restrict__ bias, const float* __restrict__ dinv,
                         float* __restrict__ tmp, float* __restrict__ outi) {
    __shared__ float Wl[IN_DIM * HID];
    int tid = threadIdx.x;  // 256 = 8 rows x 32 cols
    for (int idx = tid; idx < IN_DIM * HID; idx += 256) Wl[idx] = W[idx];
    __syncthreads();
    int row = blockIdx.x * 8 + (tid >> 5);
    if (row >= NN) return;
    int k = tid & 31;
    const float* xr = in + (size_t)row * IN_DIM;
    float acc = 0.f;
#pragma unroll 8
    for (int j = 0; j < IN_DIM; ++j) {
        float v = xr[j];
        if (RELU_IN) v = fmaxf(v, 0.f);
        acc = fmaf(v, Wl[j * HID + k], acc);
    }
    int idx = row * HID + k;
    tmp[idx] = acc;
    float di = dinv[row];
    outi[idx] = bias[k] + di * di * acc;
}

// one wave per dest node: 64 lanes = 32 feats x 2 edge slots; dual accumulator
// for 2x memory-level parallelism; no atomics.
__global__ void aggregate(const int2* __restrict__ srn, const int* __restrict__ rowptr,
                          const float* __restrict__ dinv,
                          const float* __restrict__ tmp, float* __restrict__ h) {
    int wid = (blockIdx.x * 256 + threadIdx.x) >> 6;
    if (wid >= NN) return;
    int lane = threadIdx.x & 63;
    int eo = lane >> 5, k = lane & 31;
    int end = rowptr[wid];
    int start = (wid == 0) ? 0 : rowptr[wid - 1];
    float acc0 = 0.f, acc1 = 0.f;
    int e = start + eo;
    for (; e + 2 < end; e += 4) {
        int2 p0 = srn[e];
        int2 p1 = srn[e + 2];
        acc0 = fmaf(__int_as_float(p0.y), tmp[(size_t)p0.x * HID + k], acc0);
        acc1 = fmaf(__int_as_float(p1.y), tmp[(size_t)p1.x * HID + k], acc1);
    }
    if (e < end) {
        int2 p = srn[e];
        acc0 = fmaf(__int_as_float(p.y), tmp[(size_t)p.x * HID + k], acc0);
    }
    float acc = acc0 + acc1;
    acc += __shfl_xor(acc, 32, 64);
    if (eo == 0) {
        int idx = wid * HID + k;
        h[idx] += dinv[wid] * acc;
    }
}

// sorted-batch run-length pooling
__global__ void pool_k(const float* __restrict__ h, const int* __restrict__ batch,
                       float* __restrict__ sums, float* __restrict__ counts) {
    int t = blockIdx.x * 256 + threadIdx.x;
    int chunk = t >> 5, k = t & 31;
    int n0 = chunk * 32;
    if (n0 >= NN) return;
    int n1 = min(n0 + 32, NN);
    int g = batch[n0];
    float acc = 0.f, cacc = 0.f;
    for (int i = n0; i < n1; ++i) {
        int gi = batch[i];
        if (gi != g) {
            atomicAdd(&sums[g * HID + k], acc);
            if (k == 0) atomicAdd(&counts[g], cacc);
            g = gi; acc = 0.f; cacc = 0.f;
        }
        acc += h[(size_t)i * HID + k];
        cacc += 1.f;
    }
    atomicAdd(&sums[g * HID + k], acc);
    if (k == 0) atomicAdd(&counts[g], cacc);
}

// whole MLP in one block
__global__ void mlp_k(const float* __restrict__ sums, const float* __restrict__ counts,
                      const float* __restrict__ Wm0, const float* __restrict__ bm0,
                      const float* __restrict__ Wm1, const float* __restrict__ bm1,
                      const float* __restrict__ Wout, const float* __restrict__ bout,
                      float* __restrict__ out) {
    __shared__ float g0[NG * HID];
    __shared__ float g1[NG * MH];
    __shared__ float g2[NG * MH];
    int tid = threadIdx.x;
    for (int idx = tid; idx < NG * HID; idx += 256) {
        int g = idx / HID;
        g0[idx] = sums[idx] / fmaxf(counts[g], 1.0f);
    }
    __syncthreads();
    for (int idx = tid; idx < NG * MH; idx += 256) {
        int g = idx / MH, k = idx % MH;
        float acc = bm0[k];
        for (int j = 0; j < HID; ++j) acc = fmaf(g0[g * HID + j], Wm0[j * MH + k], acc);
        g1[idx] = fmaxf(acc, 0.f);
    }
    __syncthreads();
    for (int idx = tid; idx < NG * MH; idx += 256) {
        int g = idx / MH, k = idx % MH;
        float acc = bm1[k];
        for (int j = 0; j < MH; ++j) acc = fmaf(g1[g * MH + j], Wm1[j * MH + k], acc);
        g2[idx] = fmaxf(acc, 0.f);
    }
    __syncthreads();
    for (int idx = tid; idx < NG * NC; idx += 256) {
        int g = idx / NC, k = idx % NC;
        float acc = bout[k];
        for (int j = 0; j < MH; ++j) acc = fmaf(g2[g * MH + j], Wout[j * NC + k], acc);
        out[idx] = acc;
    }
}

extern "C" void kernel_launch(void* const* d_in, const int* in_sizes, int n_in,
                              void* d_out, int out_size, void* d_ws, size_t ws_size,
                              hipStream_t stream) {
    const float* x    = (const float*)d_in[0];
    const int*   ei   = (const int*)d_in[1];
    const float* ew   = (const float*)d_in[2];
    const int*   batch= (const int*)d_in[3];
    const float* W1   = (const float*)d_in[4];
    const float* b1   = (const float*)d_in[5];
    const float* W2   = (const float*)d_in[6];
    const float* b2   = (const float*)d_in[7];
    const float* W3   = (const float*)d_in[8];
    const float* b3   = (const float*)d_in[9];
    const float* Wm0  = (const float*)d_in[10];
    const float* bm0  = (const float*)d_in[11];
    const float* Wm1  = (const float*)d_in[12];
    const float* bm1  = (const float*)d_in[13];
    const float* Wout = (const float*)d_in[14];
    const float* bout = (const float*)d_in[15];
    float* out = (float*)d_out;

    // workspace: srn | sharedRegion(tre <-> tmp+hA+hB) | scan bufs | dinv | rowptr | sums
    char* p = (char*)d_ws;
    int2*  srn = (int2*)p;               p += sizeof(int2) * (size_t)NE;      // 25.6 MB
    char*  S   = p;                      p += 12 * (size_t)NE;                // 38.4 MB shared
    int2*  tre = (int2*)S;
    float* tmp = (float*)S;
    float* hA  = tmp + (size_t)NN * HID;
    float* hB  = hA + (size_t)NN * HID;
    int*   cnt2    = (int*)p;            p += sizeof(int) * SCANL;
    int*   scanned = (int*)p;            p += sizeof(int) * SCANL;
    int*   bsum    = (int*)p;            p += sizeof(int) * 256;
    float* dinv    = (float*)p;          p += sizeof(float) * NN;
    int*   rowptr  = (int*)p;            p += sizeof(int) * NN;
    float* sums    = (float*)p;          p += sizeof(float) * NG * HID;
    float* counts  = (float*)p;

    dim3 blk(256);
    const int NB_SCAN = (SCANL + 1023) / 1024;  // 196

    init_misc<<<9, blk, 0, stream>>>(sums);
    hist_bkt<<<NBLK, 1024, 0, stream>>>(ei, cnt2);
    scan_block<<<NB_SCAN, blk, 0, stream>>>(cnt2, scanned, bsum, SCANL);
    scan_top<<<1, 64, 0, stream>>>(bsum, NB_SCAN);
    scan_add<<<(SCANL + 255) / 256, blk, 0, stream>>>(scanned, bsum, SCANL);
    scatter_bkt<<<NBLK, 1024, 0, stream>>>(ei, ew, cnt2, scanned, tre);
    bucket_sort<<<NBKT, 512, 0, stream>>>(tre, scanned, srn, rowptr, dinv);
    finalize_wn<<<(NE / 2 + 255) / 256, blk, 0, stream>>>((int4*)srn, dinv);

    // layer 1
    linear_k<FIN, false><<<12500, blk, 0, stream>>>(x, W1, b1, dinv, tmp, hA);
    aggregate<<<25000, blk, 0, stream>>>(srn, rowptr, dinv, tmp, hA);
    // layer 2
    linear_k<HID, true><<<12500, blk, 0, stream>>>(hA, W2, b2, dinv, tmp, hB);
    aggregate<<<25000, blk, 0, stream>>>(srn, rowptr, dinv, tmp, hB);
    // layer 3
    linear_k<HID, true><<<12500, blk, 0, stream>>>(hB, W3, b3, dinv, tmp, hA);
    aggregate<<<25000, blk, 0, stream>>>(srn, rowptr, dinv, tmp, hA);

    pool_k<<<391, blk, 0, stream>>>(hA, batch, sums, counts);
    mlp_k<<<1, blk, 0, stream>>>(sums, counts, Wm0, bm0, Wm1, bm1, Wout, bout, out);
}

// Round 6
// 650.844 us; speedup vs baseline: 7.7230x; 1.2060x over previous
//
#include <hip/hip_runtime.h>

#define NN 100000
#define NE 3200000
#define FIN 128
#define HID 32
#define MH  64
#define NC  10
#define NG  64
#define NBKT 782           // ceil(NN/128) buckets of 128 dest nodes
#define NBLK 256           // edge-pass blocks
#define EPB  (NE / NBLK)   // 12500 edges per block
#define SCANL (NBKT * NBLK)
#define SRCMASK 0x1FFFF    // src < 100000 < 2^17

// fp32 -> bf16 bits, round-to-nearest-even
__device__ __forceinline__ unsigned short f32_to_bf16(float f) {
    unsigned int u = __float_as_uint(f);
    u += 0x7FFFu + ((u >> 16) & 1u);
    return (unsigned short)(u >> 16);
}

__global__ void init_misc(float* __restrict__ sc) {
    int i = blockIdx.x * 256 + threadIdx.x;
    if (i < NG * HID + NG) sc[i] = 0.0f;
}

// per-block LDS histogram over 782 dest-buckets; no global atomics
__global__ __launch_bounds__(1024)
void hist_bkt(const int* __restrict__ ei, int* __restrict__ cnt2) {
    __shared__ int h[NBKT];
    int tid = threadIdx.x, blk = blockIdx.x;
    for (int b = tid; b < NBKT; b += 1024) h[b] = 0;
    __syncthreads();
    int base = blk * EPB;
    for (int i = tid; i < EPB; i += 1024)
        atomicAdd(&h[ei[NE + base + i] >> 7], 1);
    __syncthreads();
    for (int b = tid; b < NBKT; b += 1024) cnt2[b * NBLK + blk] = h[b];
}

// ---- generic exclusive scan (1024 elems/block) ----
__global__ void scan_block(const int* __restrict__ in, int* __restrict__ out,
                           int* __restrict__ bsum, int n) {
    __shared__ int lds[256];
    int tid = threadIdx.x;
    int base = blockIdx.x * 1024 + tid * 4;
    int v0 = 0, v1 = 0, v2 = 0, v3 = 0;
    if (base + 0 < n) v0 = in[base + 0];
    if (base + 1 < n) v1 = in[base + 1];
    if (base + 2 < n) v2 = in[base + 2];
    if (base + 3 < n) v3 = in[base + 3];
    int s = v0 + v1 + v2 + v3;
    lds[tid] = s;
    __syncthreads();
    for (int off = 1; off < 256; off <<= 1) {
        int val = (tid >= off) ? lds[tid - off] : 0;
        __syncthreads();
        lds[tid] += val;
        __syncthreads();
    }
    int excl = lds[tid] - s;
    if (tid == 255) bsum[blockIdx.x] = lds[255];
    if (base + 0 < n) out[base + 0] = excl;
    if (base + 1 < n) out[base + 1] = excl + v0;
    if (base + 2 < n) out[base + 2] = excl + v0 + v1;
    if (base + 3 < n) out[base + 3] = excl + v0 + v1 + v2;
}

__global__ void scan_top(int* __restrict__ bsum, int nb) {
    if (threadIdx.x == 0) {
        int acc = 0;
        for (int i = 0; i < nb; ++i) { int v = bsum[i]; bsum[i] = acc; acc += v; }
    }
}

__global__ void scan_add(int* __restrict__ data, const int* __restrict__ bsum, int n) {
    int i = blockIdx.x * 256 + threadIdx.x;
    if (i < n) data[i] += bsum[i >> 10];
}

// LDS counting-sort of the block's edges by bucket, then slot-major burst
// writes: consecutive lanes -> consecutive global positions (full-line writes).
__global__ __launch_bounds__(1024)
void scatter_bkt(const int* __restrict__ ei, const float* __restrict__ ew,
                 const int* __restrict__ cnt2, const int* __restrict__ scanned,
                 int2* __restrict__ tre) {
    __shared__ int sidx[EPB];      // 50 KB
    __shared__ int hinc[NBKT];
    __shared__ int hexc[NBKT];
    __shared__ int cur[NBKT];
    __shared__ int gbase[NBKT];
    int tid = threadIdx.x, blk = blockIdx.x;
    int myh = 0;
    if (tid < NBKT) {
        myh = cnt2[tid * NBLK + blk];
        gbase[tid] = scanned[tid * NBLK + blk];
        hinc[tid] = myh;
    }
    __syncthreads();
    for (int off = 1; off < NBKT; off <<= 1) {
        int v = (tid < NBKT && tid >= off) ? hinc[tid - off] : 0;
        __syncthreads();
        if (tid < NBKT) hinc[tid] += v;
        __syncthreads();
    }
    if (tid < NBKT) { int ex = hinc[tid] - myh; hexc[tid] = ex; cur[tid] = ex; }
    __syncthreads();
    int base = blk * EPB;
    for (int i = tid; i < EPB; i += 1024) {
        int b = ei[NE + base + i] >> 7;
        int j = atomicAdd(&cur[b], 1);
        sidx[j] = i;
    }
    __syncthreads();
    for (int j = tid; j < EPB; j += 1024) {
        int i = sidx[j];
        int e = base + i;
        int c = ei[NE + e];
        int b = c >> 7;
        int pos = gbase[b] + (j - hexc[b]);
        tre[pos] = make_int2(ei[e] | ((c & 127) << 17), __float_as_int(ew[e]));
    }
}

// one block per bucket: 128-bin count+scan in LDS, emit node-sorted (src, ew),
// rowptr (end offsets), and dinv = rsqrt(1 + weighted_indeg)
__global__ __launch_bounds__(512)
void bucket_sort(const int2* __restrict__ tre, const int* __restrict__ scanned,
                 int2* __restrict__ srn, int* __restrict__ rowptr,
                 float* __restrict__ dinv) {
    __shared__ int h[128];
    __shared__ float dw[128];
    __shared__ int sc[128];
    __shared__ int cur[128];
    int b = blockIdx.x, tid = threadIdx.x;
    int base = scanned[b * NBLK];
    int end = (b == NBKT - 1) ? NE : scanned[(b + 1) * NBLK];
    int n = end - base;
    if (tid < 128) { h[tid] = 0; dw[tid] = 0.f; }
    __syncthreads();
    for (int i = tid; i < n; i += 512) {
        int2 q = tre[base + i];
        int key = (q.x >> 17) & 127;
        atomicAdd(&h[key], 1);
        atomicAdd(&dw[key], __int_as_float(q.y));
    }
    __syncthreads();
    if (tid < 128) sc[tid] = h[tid];
    __syncthreads();
    for (int off = 1; off < 128; off <<= 1) {
        int v = (tid < 128 && tid >= off) ? sc[tid - off] : 0;
        __syncthreads();
        if (tid < 128) sc[tid] += v;
        __syncthreads();
    }
    if (tid < 128) {
        int node = b * 128 + tid;
        if (node < NN) {
            rowptr[node] = base + sc[tid];               // end offset
            dinv[node] = rsqrtf(1.0f + dw[tid]);         // self-loop included
        }
        cur[tid] = base + sc[tid] - h[tid];              // start cursor
    }
    __syncthreads();
    for (int i = tid; i < n; i += 512) {
        int2 q = tre[base + i];
        int key = (q.x >> 17) & 127;
        int pos = atomicAdd(&cur[key], 1);
        srn[pos] = make_int2(q.x & SRCMASK, q.y);
    }
}

// srn.y: ew -> ew * dinv[src]; 2 edges per thread via int4
__global__ void finalize_wn(int4* __restrict__ srn2, const float* __restrict__ dinv) {
    int t = blockIdx.x * 256 + threadIdx.x;
    if (t < NE / 2) {
        int4 q = srn2[t];
        q.y = __float_as_int(__int_as_float(q.y) * dinv[q.x]);
        q.w = __float_as_int(__int_as_float(q.w) * dinv[q.z]);
        srn2[t] = q;
    }
}

// tmpb = bf16(act(in) @ W) ; outi = bias + dinv^2 * acc (fp32 self-loop path).
// thread = (col k, 2 rows); float4 x loads; W in LDS read once per 2 rows.
template <int IN_DIM, bool RELU_IN>
__global__ void linear_k(const float* __restrict__ in, const float* __restrict__ W,
                         const float* __restrict__ bias, const float* __restrict__ dinv,
                         unsigned short* __restrict__ tmpb, float* __restrict__ outi) {
    __shared__ float Wl[IN_DIM * HID];
    int tid = threadIdx.x;
    for (int idx = tid; idx < IN_DIM * HID; idx += 256) Wl[idx] = W[idx];
    __syncthreads();
    int k = tid & 31;
    int a = tid >> 5;                   // 0..7
    int r0 = blockIdx.x * 16 + a * 2;   // NN % 16 == 0, always in range
    const float4* x0 = (const float4*)(in + (size_t)r0 * IN_DIM);
    const float4* x1 = (const float4*)(in + (size_t)(r0 + 1) * IN_DIM);
    float acc0 = 0.f, acc1 = 0.f;
#pragma unroll
    for (int j4 = 0; j4 < IN_DIM / 4; ++j4) {
        float4 v0 = x0[j4];
        float4 v1 = x1[j4];
        if (RELU_IN) {
            v0.x = fmaxf(v0.x, 0.f); v0.y = fmaxf(v0.y, 0.f);
            v0.z = fmaxf(v0.z, 0.f); v0.w = fmaxf(v0.w, 0.f);
            v1.x = fmaxf(v1.x, 0.f); v1.y = fmaxf(v1.y, 0.f);
            v1.z = fmaxf(v1.z, 0.f); v1.w = fmaxf(v1.w, 0.f);
        }
        const float* wp = &Wl[j4 * 4 * HID + k];
        float w0 = wp[0], w1 = wp[HID], w2 = wp[2 * HID], w3 = wp[3 * HID];
        acc0 = fmaf(v0.x, w0, acc0); acc0 = fmaf(v0.y, w1, acc0);
        acc0 = fmaf(v0.z, w2, acc0); acc0 = fmaf(v0.w, w3, acc0);
        acc1 = fmaf(v1.x, w0, acc1); acc1 = fmaf(v1.y, w1, acc1);
        acc1 = fmaf(v1.z, w2, acc1); acc1 = fmaf(v1.w, w3, acc1);
    }
    float bk = bias[k];
    int idx0 = r0 * HID + k;
    float d0 = dinv[r0], d1 = dinv[r0 + 1];
    tmpb[idx0] = f32_to_bf16(acc0);
    tmpb[idx0 + HID] = f32_to_bf16(acc1);
    outi[idx0] = bk + d0 * d0 * acc0;
    outi[idx0 + HID] = bk + d1 * d1 * acc1;
}

// one wave per dest node: 64 lanes = 16 feat-pairs x 4 edge slots.
// each lane gathers ushort2 (bf16 pair) -> 64B line per edge; 2 gathers in flight.
__global__ void aggregate(const int2* __restrict__ srn, const int* __restrict__ rowptr,
                          const float* __restrict__ dinv,
                          const unsigned short* __restrict__ tmpb, float* __restrict__ h) {
    int wid = (blockIdx.x * 256 + threadIdx.x) >> 6;
    if (wid >= NN) return;
    int lane = threadIdx.x & 63;
    int g = lane >> 4;      // edge slot 0..3
    int q = lane & 15;      // feat pair (feats 2q, 2q+1)
    int end = rowptr[wid];
    int start = (wid == 0) ? 0 : rowptr[wid - 1];
    float a0x = 0.f, a0y = 0.f, a1x = 0.f, a1y = 0.f;
    int e = start + g;
    for (; e + 4 < end; e += 8) {
        int2 p0 = srn[e];
        int2 p1 = srn[e + 4];
        unsigned int u0 = *(const unsigned int*)(tmpb + (size_t)p0.x * HID + 2 * q);
        unsigned int u1 = *(const unsigned int*)(tmpb + (size_t)p1.x * HID + 2 * q);
        float w0 = __int_as_float(p0.y), w1 = __int_as_float(p1.y);
        a0x = fmaf(w0, __int_as_float((int)(u0 << 16)), a0x);
        a0y = fmaf(w0, __int_as_float((int)(u0 & 0xFFFF0000u)), a0y);
        a1x = fmaf(w1, __int_as_float((int)(u1 << 16)), a1x);
        a1y = fmaf(w1, __int_as_float((int)(u1 & 0xFFFF0000u)), a1y);
    }
    if (e < end) {
        int2 p = srn[e];
        unsigned int u = *(const unsigned int*)(tmpb + (size_t)p.x * HID + 2 * q);
        float w = __int_as_float(p.y);
        a0x = fmaf(w, __int_as_float((int)(u << 16)), a0x);
        a0y = fmaf(w, __int_as_float((int)(u & 0xFFFF0000u)), a0y);
    }
    float ax = a0x + a1x, ay = a0y + a1y;
    ax += __shfl_xor(ax, 16, 64); ay += __shfl_xor(ay, 16, 64);
    ax += __shfl_xor(ax, 32, 64); ay += __shfl_xor(ay, 32, 64);
    if (g == 0) {
        float d = dinv[wid];
        float2* hp = (float2*)(h + (size_t)wid * HID);
        float2 o = hp[q];
        o.x += d * ax; o.y += d * ay;
        hp[q] = o;
    }
}

// sorted-batch run-length pooling
__global__ void pool_k(const float* __restrict__ h, const int* __restrict__ batch,
                       float* __restrict__ sums, float* __restrict__ counts) {
    int t = blockIdx.x * 256 + threadIdx.x;
    int chunk = t >> 5, k = t & 31;
    int n0 = chunk * 32;
    if (n0 >= NN) return;
    int n1 = min(n0 + 32, NN);
    int g = batch[n0];
    float acc = 0.f, cacc = 0.f;
    for (int i = n0; i < n1; ++i) {
        int gi = batch[i];
        if (gi != g) {
            atomicAdd(&sums[g * HID + k], acc);
            if (k == 0) atomicAdd(&counts[g], cacc);
            g = gi; acc = 0.f; cacc = 0.f;
        }
        acc += h[(size_t)i * HID + k];
        cacc += 1.f;
    }
    atomicAdd(&sums[g * HID + k], acc);
    if (k == 0) atomicAdd(&counts[g], cacc);
}

// whole MLP in one block
__global__ void mlp_k(const float* __restrict__ sums, const float* __restrict__ counts,
                      const float* __restrict__ Wm0, const float* __restrict__ bm0,
                      const float* __restrict__ Wm1, const float* __restrict__ bm1,
                      const float* __restrict__ Wout, const float* __restrict__ bout,
                      float* __restrict__ out) {
    __shared__ float g0[NG * HID];
    __shared__ float g1[NG * MH];
    __shared__ float g2[NG * MH];
    int tid = threadIdx.x;
    for (int idx = tid; idx < NG * HID; idx += 256) {
        int g = idx / HID;
        g0[idx] = sums[idx] / fmaxf(counts[g], 1.0f);
    }
    __syncthreads();
    for (int idx = tid; idx < NG * MH; idx += 256) {
        int g = idx / MH, k = idx % MH;
        float acc = bm0[k];
        for (int j = 0; j < HID; ++j) acc = fmaf(g0[g * HID + j], Wm0[j * MH + k], acc);
        g1[idx] = fmaxf(acc, 0.f);
    }
    __syncthreads();
    for (int idx = tid; idx < NG * MH; idx += 256) {
        int g = idx / MH, k = idx % MH;
        float acc = bm1[k];
        for (int j = 0; j < MH; ++j) acc = fmaf(g1[g * MH + j], Wm1[j * MH + k], acc);
        g2[idx] = fmaxf(acc, 0.f);
    }
    __syncthreads();
    for (int idx = tid; idx < NG * NC; idx += 256) {
        int g = idx / NC, k = idx % NC;
        float acc = bout[k];
        for (int j = 0; j < MH; ++j) acc = fmaf(g2[g * MH + j], Wout[j * NC + k], acc);
        out[idx] = acc;
    }
}

extern "C" void kernel_launch(void* const* d_in, const int* in_sizes, int n_in,
                              void* d_out, int out_size, void* d_ws, size_t ws_size,
                              hipStream_t stream) {
    const float* x    = (const float*)d_in[0];
    const int*   ei   = (const int*)d_in[1];
    const float* ew   = (const float*)d_in[2];
    const int*   batch= (const int*)d_in[3];
    const float* W1   = (const float*)d_in[4];
    const float* b1   = (const float*)d_in[5];
    const float* W2   = (const float*)d_in[6];
    const float* b2   = (const float*)d_in[7];
    const float* W3   = (const float*)d_in[8];
    const float* b3   = (const float*)d_in[9];
    const float* Wm0  = (const float*)d_in[10];
    const float* bm0  = (const float*)d_in[11];
    const float* Wm1  = (const float*)d_in[12];
    const float* bm1  = (const float*)d_in[13];
    const float* Wout = (const float*)d_in[14];
    const float* bout = (const float*)d_in[15];
    float* out = (float*)d_out;

    // workspace: srn | sharedRegion(tre <-> tmpb+hA+hB) | scan bufs | dinv | rowptr | sums
    char* p = (char*)d_ws;
    int2*  srn = (int2*)p;               p += sizeof(int2) * (size_t)NE;      // 25.6 MB
    char*  S   = p;                      p += 12 * (size_t)NE;                // 38.4 MB shared
    int2*  tre = (int2*)S;
    unsigned short* tmpb = (unsigned short*)S;                                // 6.4 MB
    float* hA  = (float*)(S + 2 * (size_t)NN * HID);
    float* hB  = hA + (size_t)NN * HID;
    int*   cnt2    = (int*)p;            p += sizeof(int) * SCANL;
    int*   scanned = (int*)p;            p += sizeof(int) * SCANL;
    int*   bsum    = (int*)p;            p += sizeof(int) * 256;
    float* dinv    = (float*)p;          p += sizeof(float) * NN;
    int*   rowptr  = (int*)p;            p += sizeof(int) * NN;
    float* sums    = (float*)p;          p += sizeof(float) * NG * HID;
    float* counts  = (float*)p;

    dim3 blk(256);
    const int NB_SCAN = (SCANL + 1023) / 1024;  // 196

    init_misc<<<9, blk, 0, stream>>>(sums);
    hist_bkt<<<NBLK, 1024, 0, stream>>>(ei, cnt2);
    scan_block<<<NB_SCAN, blk, 0, stream>>>(cnt2, scanned, bsum, SCANL);
    scan_top<<<1, 64, 0, stream>>>(bsum, NB_SCAN);
    scan_add<<<(SCANL + 255) / 256, blk, 0, stream>>>(scanned, bsum, SCANL);
    scatter_bkt<<<NBLK, 1024, 0, stream>>>(ei, ew, cnt2, scanned, tre);
    bucket_sort<<<NBKT, 512, 0, stream>>>(tre, scanned, srn, rowptr, dinv);
    finalize_wn<<<(NE / 2 + 255) / 256, blk, 0, stream>>>((int4*)srn, dinv);

    // layer 1
    linear_k<FIN, false><<<6250, blk, 0, stream>>>(x, W1, b1, dinv, tmpb, hA);
    aggregate<<<25000, blk, 0, stream>>>(srn, rowptr, dinv, tmpb, hA);
    // layer 2
    linear_k<HID, true><<<6250, blk, 0, stream>>>(hA, W2, b2, dinv, tmpb, hB);
    aggregate<<<25000, blk, 0, stream>>>(srn, rowptr, dinv, tmpb, hB);
    // layer 3
    linear_k<HID, true><<<6250, blk, 0, stream>>>(hB, W3, b3, dinv, tmpb, hA);
    aggregate<<<25000, blk, 0, stream>>>(srn, rowptr, dinv, tmpb, hA);

    pool_k<<<391, blk, 0, stream>>>(hA, batch, sums, counts);
    mlp_k<<<1, blk, 0, stream>>>(sums, counts, Wm0, bm0, Wm1, bm1, Wout, bout, out);
}

// Round 7
// 559.078 us; speedup vs baseline: 8.9907x; 1.1641x over previous
//
#include <hip/hip_runtime.h>

#define NN 100000
#define NE 3200000
#define FIN 128
#define HID 32
#define MH  64
#define NC  10
#define NG  64
#define NBKT 782           // ceil(NN/128) buckets of 128 dest nodes
#define NBLK 256           // edge-pass blocks
#define EPB  (NE / NBLK)   // 12500 edges per block
#define SCANL (NBKT * NBLK)
#define SRCMASK 0x1FFFF    // src < 100000 < 2^17
#define BCAP 5120          // bucket LDS capacity (mean 4092, sd 64 -> 16 sd headroom)

// fp32 -> bf16 bits, round-to-nearest-even
__device__ __forceinline__ unsigned short f32_to_bf16(float f) {
    unsigned int u = __float_as_uint(f);
    u += 0x7FFFu + ((u >> 16) & 1u);
    return (unsigned short)(u >> 16);
}

__global__ void init_misc(float* __restrict__ sc) {
    int i = blockIdx.x * 256 + threadIdx.x;
    if (i < NG * HID + NG) sc[i] = 0.0f;
}

// per-block LDS histogram over 782 dest-buckets; no global atomics
__global__ __launch_bounds__(1024)
void hist_bkt(const int* __restrict__ ei, int* __restrict__ cnt2) {
    __shared__ int h[NBKT];
    int tid = threadIdx.x, blk = blockIdx.x;
    for (int b = tid; b < NBKT; b += 1024) h[b] = 0;
    __syncthreads();
    int base = blk * EPB;
    for (int i = tid; i < EPB; i += 1024)
        atomicAdd(&h[ei[NE + base + i] >> 7], 1);
    __syncthreads();
    for (int b = tid; b < NBKT; b += 1024) cnt2[b * NBLK + blk] = h[b];
}

// ---- generic exclusive scan (1024 elems/block) ----
__global__ void scan_block(const int* __restrict__ in, int* __restrict__ out,
                           int* __restrict__ bsum, int n) {
    __shared__ int lds[256];
    int tid = threadIdx.x;
    int base = blockIdx.x * 1024 + tid * 4;
    int v0 = 0, v1 = 0, v2 = 0, v3 = 0;
    if (base + 0 < n) v0 = in[base + 0];
    if (base + 1 < n) v1 = in[base + 1];
    if (base + 2 < n) v2 = in[base + 2];
    if (base + 3 < n) v3 = in[base + 3];
    int s = v0 + v1 + v2 + v3;
    lds[tid] = s;
    __syncthreads();
    for (int off = 1; off < 256; off <<= 1) {
        int val = (tid >= off) ? lds[tid - off] : 0;
        __syncthreads();
        lds[tid] += val;
        __syncthreads();
    }
    int excl = lds[tid] - s;
    if (tid == 255) bsum[blockIdx.x] = lds[255];
    if (base + 0 < n) out[base + 0] = excl;
    if (base + 1 < n) out[base + 1] = excl + v0;
    if (base + 2 < n) out[base + 2] = excl + v0 + v1;
    if (base + 3 < n) out[base + 3] = excl + v0 + v1 + v2;
}

__global__ void scan_top(int* __restrict__ bsum, int nb) {
    if (threadIdx.x == 0) {
        int acc = 0;
        for (int i = 0; i < nb; ++i) { int v = bsum[i]; bsum[i] = acc; acc += v; }
    }
}

__global__ void scan_add(int* __restrict__ data, const int* __restrict__ bsum, int n) {
    int i = blockIdx.x * 256 + threadIdx.x;
    if (i < n) data[i] += bsum[i >> 10];
}

// LDS counting-sort of the block's edges by bucket, then slot-major burst writes
__global__ __launch_bounds__(1024)
void scatter_bkt(const int* __restrict__ ei, const float* __restrict__ ew,
                 const int* __restrict__ cnt2, const int* __restrict__ scanned,
                 int2* __restrict__ tre) {
    __shared__ int sidx[EPB];      // 50 KB
    __shared__ int hinc[NBKT];
    __shared__ int hexc[NBKT];
    __shared__ int cur[NBKT];
    __shared__ int gbase[NBKT];
    int tid = threadIdx.x, blk = blockIdx.x;
    int myh = 0;
    if (tid < NBKT) {
        myh = cnt2[tid * NBLK + blk];
        gbase[tid] = scanned[tid * NBLK + blk];
        hinc[tid] = myh;
    }
    __syncthreads();
    for (int off = 1; off < NBKT; off <<= 1) {
        int v = (tid < NBKT && tid >= off) ? hinc[tid - off] : 0;
        __syncthreads();
        if (tid < NBKT) hinc[tid] += v;
        __syncthreads();
    }
    if (tid < NBKT) { int ex = hinc[tid] - myh; hexc[tid] = ex; cur[tid] = ex; }
    __syncthreads();
    int base = blk * EPB;
    for (int i = tid; i < EPB; i += 1024) {
        int b = ei[NE + base + i] >> 7;
        int j = atomicAdd(&cur[b], 1);
        sidx[j] = i;
    }
    __syncthreads();
    for (int j = tid; j < EPB; j += 1024) {
        int i = sidx[j];
        int e = base + i;
        int c = ei[NE + e];
        int b = c >> 7;
        int pos = gbase[b] + (j - hexc[b]);
        tre[pos] = make_int2(ei[e] | ((c & 127) << 17), __float_as_int(ew[e]));
    }
}

// one block per bucket: stage bucket edges in LDS (single global read),
// 128-bin count+scan, emit node-sorted (src, ew), rowptr, dinv
__global__ __launch_bounds__(512)
void bucket_sort(const int2* __restrict__ tre, const int* __restrict__ scanned,
                 int2* __restrict__ srn, int* __restrict__ rowptr,
                 float* __restrict__ dinv) {
    __shared__ int2 ed[BCAP];      // 40 KB
    __shared__ int h[128];
    __shared__ float dw[128];
    __shared__ int sc[128];
    __shared__ int cur[128];
    int b = blockIdx.x, tid = threadIdx.x;
    int base = scanned[b * NBLK];
    int end = (b == NBKT - 1) ? NE : scanned[(b + 1) * NBLK];
    int n = end - base;
    bool staged = (n <= BCAP);
    if (tid < 128) { h[tid] = 0; dw[tid] = 0.f; }
    if (staged)
        for (int i = tid; i < n; i += 512) ed[i] = tre[base + i];
    __syncthreads();
    for (int i = tid; i < n; i += 512) {
        int2 q = staged ? ed[i] : tre[base + i];
        int key = (q.x >> 17) & 127;
        atomicAdd(&h[key], 1);
        atomicAdd(&dw[key], __int_as_float(q.y));
    }
    __syncthreads();
    if (tid < 128) sc[tid] = h[tid];
    __syncthreads();
    for (int off = 1; off < 128; off <<= 1) {
        int v = (tid < 128 && tid >= off) ? sc[tid - off] : 0;
        __syncthreads();
        if (tid < 128) sc[tid] += v;
        __syncthreads();
    }
    if (tid < 128) {
        int node = b * 128 + tid;
        if (node < NN) {
            rowptr[node] = base + sc[tid];               // end offset
            dinv[node] = rsqrtf(1.0f + dw[tid]);         // self-loop included
        }
        cur[tid] = base + sc[tid] - h[tid];              // start cursor
    }
    __syncthreads();
    for (int i = tid; i < n; i += 512) {
        int2 q = staged ? ed[i] : tre[base + i];
        int key = (q.x >> 17) & 127;
        int pos = atomicAdd(&cur[key], 1);
        srn[pos] = make_int2(q.x & SRCMASK, q.y);
    }
}

// srn.y: ew -> ew * dinv[src]; 2 edges per thread via int4
__global__ void finalize_wn(int4* __restrict__ srn2, const float* __restrict__ dinv) {
    int t = blockIdx.x * 256 + threadIdx.x;
    if (t < NE / 2) {
        int4 q = srn2[t];
        q.y = __float_as_int(__int_as_float(q.y) * dinv[q.x]);
        q.w = __float_as_int(__int_as_float(q.w) * dinv[q.z]);
        srn2[t] = q;
    }
}

// LDS-tiled linear: 64-row x tile (padded, coalesced staging, relu folded),
// W pre-swizzled to wp[j][kg] = {W[j][kg], W[j][kg+8], W[j][kg+16], W[j][kg+24]}.
// thread = 2 rows x 4 cols (cols kg+8*kk), all inner reads are ds_read_b128.
template <int IN_DIM, bool RELU_IN>
__global__ __launch_bounds__(256)
void linear_k(const float* __restrict__ in, const float* __restrict__ W,
              const float* __restrict__ bias, const float* __restrict__ dinv,
              unsigned short* __restrict__ tmpb, float* __restrict__ outi) {
    constexpr int J4 = IN_DIM / 4;       // 32 or 8
    constexpr int XSS = J4 + 1;          // padded row stride (float4)
    __shared__ float4 xs[64 * XSS];
    __shared__ float4 wp[IN_DIM * 8];
    int tid = threadIdx.x;
    for (int idx = tid; idx < IN_DIM * 8; idx += 256) {
        int j = idx >> 3, kg = idx & 7;
        const float* wr = W + j * 32 + kg;
        wp[idx] = make_float4(wr[0], wr[8], wr[16], wr[24]);
    }
    int rbase = blockIdx.x * 64;
    const float4* in4 = (const float4*)in;
    for (int idx = tid; idx < 64 * J4; idx += 256) {
        int row = idx / J4, j4 = idx % J4;   // J4 is pow2 -> shifts
        int grow = rbase + row;
        float4 v = (grow < NN) ? in4[(size_t)grow * J4 + j4]
                               : make_float4(0.f, 0.f, 0.f, 0.f);
        if (RELU_IN) {
            v.x = fmaxf(v.x, 0.f); v.y = fmaxf(v.y, 0.f);
            v.z = fmaxf(v.z, 0.f); v.w = fmaxf(v.w, 0.f);
        }
        xs[row * XSS + j4] = v;
    }
    __syncthreads();
    int kg = tid & 7;          // cols kg + 8*kk
    int rp = tid >> 3;         // rows 2rp, 2rp+1
    int r0 = rbase + 2 * rp;
    if (r0 >= NN) return;
    const float4* x0 = &xs[(2 * rp) * XSS];
    const float4* x1 = &xs[(2 * rp + 1) * XSS];
    float a00 = 0, a01 = 0, a02 = 0, a03 = 0;
    float a10 = 0, a11 = 0, a12 = 0, a13 = 0;
#pragma unroll
    for (int j4 = 0; j4 < J4; ++j4) {
        float4 v0 = x0[j4], v1 = x1[j4];
        const float4* wj = &wp[j4 * 4 * 8 + kg];
        float4 w0 = wj[0], w1 = wj[8], w2 = wj[16], w3 = wj[24];
#define LSTEP(VX0, VX1, W4) \
        a00 = fmaf(VX0, W4.x, a00); a01 = fmaf(VX0, W4.y, a01); \
        a02 = fmaf(VX0, W4.z, a02); a03 = fmaf(VX0, W4.w, a03); \
        a10 = fmaf(VX1, W4.x, a10); a11 = fmaf(VX1, W4.y, a11); \
        a12 = fmaf(VX1, W4.z, a12); a13 = fmaf(VX1, W4.w, a13);
        LSTEP(v0.x, v1.x, w0)
        LSTEP(v0.y, v1.y, w1)
        LSTEP(v0.z, v1.z, w2)
        LSTEP(v0.w, v1.w, w3)
#undef LSTEP
    }
    float bk0 = bias[kg], bk1 = bias[kg + 8], bk2 = bias[kg + 16], bk3 = bias[kg + 24];
    float d0 = dinv[r0], d1 = dinv[r0 + 1];
    int o0 = r0 * HID + kg;
    int o1 = o0 + HID;
    tmpb[o0] = f32_to_bf16(a00); tmpb[o0 + 8] = f32_to_bf16(a01);
    tmpb[o0 + 16] = f32_to_bf16(a02); tmpb[o0 + 24] = f32_to_bf16(a03);
    tmpb[o1] = f32_to_bf16(a10); tmpb[o1 + 8] = f32_to_bf16(a11);
    tmpb[o1 + 16] = f32_to_bf16(a12); tmpb[o1 + 24] = f32_to_bf16(a13);
    float s0 = d0 * d0, s1 = d1 * d1;
    outi[o0] = bk0 + s0 * a00; outi[o0 + 8] = bk1 + s0 * a01;
    outi[o0 + 16] = bk2 + s0 * a02; outi[o0 + 24] = bk3 + s0 * a03;
    outi[o1] = bk0 + s1 * a10; outi[o1 + 8] = bk1 + s1 * a11;
    outi[o1 + 16] = bk2 + s1 * a12; outi[o1 + 24] = bk3 + s1 * a13;
}

// one wave per dest node: 64 lanes = 8 feat-quads x 8 edge slots.
// lane gathers uint2 (4 bf16 feats, 8B); 2 gathers in flight; float4 epilogue.
__global__ void aggregate(const int2* __restrict__ srn, const int* __restrict__ rowptr,
                          const float* __restrict__ dinv,
                          const unsigned short* __restrict__ tmpb, float* __restrict__ h) {
    int wid = (blockIdx.x * 256 + threadIdx.x) >> 6;
    if (wid >= NN) return;
    int lane = threadIdx.x & 63;
    int g = lane >> 3;      // edge slot 0..7
    int q = lane & 7;       // feat quad (feats 4q..4q+3)
    int end = rowptr[wid];
    int start = (wid == 0) ? 0 : rowptr[wid - 1];
    float a0 = 0, a1 = 0, a2 = 0, a3 = 0;
    float b0 = 0, b1 = 0, b2 = 0, b3 = 0;
    int e = start + g;
    for (; e + 8 < end; e += 16) {
        int2 p0 = srn[e];
        int2 p1 = srn[e + 8];
        uint2 u0 = *(const uint2*)(tmpb + (size_t)p0.x * HID + 4 * q);
        uint2 u1 = *(const uint2*)(tmpb + (size_t)p1.x * HID + 4 * q);
        float w0 = __int_as_float(p0.y), w1 = __int_as_float(p1.y);
        a0 = fmaf(w0, __int_as_float((int)(u0.x << 16)), a0);
        a1 = fmaf(w0, __int_as_float((int)(u0.x & 0xFFFF0000u)), a1);
        a2 = fmaf(w0, __int_as_float((int)(u0.y << 16)), a2);
        a3 = fmaf(w0, __int_as_float((int)(u0.y & 0xFFFF0000u)), a3);
        b0 = fmaf(w1, __int_as_float((int)(u1.x << 16)), b0);
        b1 = fmaf(w1, __int_as_float((int)(u1.x & 0xFFFF0000u)), b1);
        b2 = fmaf(w1, __int_as_float((int)(u1.y << 16)), b2);
        b3 = fmaf(w1, __int_as_float((int)(u1.y & 0xFFFF0000u)), b3);
    }
    if (e < end) {
        int2 p = srn[e];
        uint2 u = *(const uint2*)(tmpb + (size_t)p.x * HID + 4 * q);
        float w = __int_as_float(p.y);
        a0 = fmaf(w, __int_as_float((int)(u.x << 16)), a0);
        a1 = fmaf(w, __int_as_float((int)(u.x & 0xFFFF0000u)), a1);
        a2 = fmaf(w, __int_as_float((int)(u.y << 16)), a2);
        a3 = fmaf(w, __int_as_float((int)(u.y & 0xFFFF0000u)), a3);
    }
    a0 += b0; a1 += b1; a2 += b2; a3 += b3;
    a0 += __shfl_xor(a0, 8, 64); a1 += __shfl_xor(a1, 8, 64);
    a2 += __shfl_xor(a2, 8, 64); a3 += __shfl_xor(a3, 8, 64);
    a0 += __shfl_xor(a0, 16, 64); a1 += __shfl_xor(a1, 16, 64);
    a2 += __shfl_xor(a2, 16, 64); a3 += __shfl_xor(a3, 16, 64);
    a0 += __shfl_xor(a0, 32, 64); a1 += __shfl_xor(a1, 32, 64);
    a2 += __shfl_xor(a2, 32, 64); a3 += __shfl_xor(a3, 32, 64);
    if (g == 0) {
        float d = dinv[wid];
        float4* hp = (float4*)(h + (size_t)wid * HID);
        float4 o = hp[q];
        o.x += d * a0; o.y += d * a1; o.z += d * a2; o.w += d * a3;
        hp[q] = o;
    }
}

// sorted-batch run-length pooling
__global__ void pool_k(const float* __restrict__ h, const int* __restrict__ batch,
                       float* __restrict__ sums, float* __restrict__ counts) {
    int t = blockIdx.x * 256 + threadIdx.x;
    int chunk = t >> 5, k = t & 31;
    int n0 = chunk * 32;
    if (n0 >= NN) return;
    int n1 = min(n0 + 32, NN);
    int g = batch[n0];
    float acc = 0.f, cacc = 0.f;
    for (int i = n0; i < n1; ++i) {
        int gi = batch[i];
        if (gi != g) {
            atomicAdd(&sums[g * HID + k], acc);
            if (k == 0) atomicAdd(&counts[g], cacc);
            g = gi; acc = 0.f; cacc = 0.f;
        }
        acc += h[(size_t)i * HID + k];
        cacc += 1.f;
    }
    atomicAdd(&sums[g * HID + k], acc);
    if (k == 0) atomicAdd(&counts[g], cacc);
}

// whole MLP in one block
__global__ void mlp_k(const float* __restrict__ sums, const float* __restrict__ counts,
                      const float* __restrict__ Wm0, const float* __restrict__ bm0,
                      const float* __restrict__ Wm1, const float* __restrict__ bm1,
                      const float* __restrict__ Wout, const float* __restrict__ bout,
                      float* __restrict__ out) {
    __shared__ float g0[NG * HID];
    __shared__ float g1[NG * MH];
    __shared__ float g2[NG * MH];
    int tid = threadIdx.x;
    for (int idx = tid; idx < NG * HID; idx += 256) {
        int g = idx / HID;
        g0[idx] = sums[idx] / fmaxf(counts[g], 1.0f);
    }
    __syncthreads();
    for (int idx = tid; idx < NG * MH; idx += 256) {
        int g = idx / MH, k = idx % MH;
        float acc = bm0[k];
        for (int j = 0; j < HID; ++j) acc = fmaf(g0[g * HID + j], Wm0[j * MH + k], acc);
        g1[idx] = fmaxf(acc, 0.f);
    }
    __syncthreads();
    for (int idx = tid; idx < NG * MH; idx += 256) {
        int g = idx / MH, k = idx % MH;
        float acc = bm1[k];
        for (int j = 0; j < MH; ++j) acc = fmaf(g1[g * MH + j], Wm1[j * MH + k], acc);
        g2[idx] = fmaxf(acc, 0.f);
    }
    __syncthreads();
    for (int idx = tid; idx < NG * NC; idx += 256) {
        int g = idx / NC, k = idx % NC;
        float acc = bout[k];
        for (int j = 0; j < MH; ++j) acc = fmaf(g2[g * MH + j], Wout[j * NC + k], acc);
        out[idx] = acc;
    }
}

extern "C" void kernel_launch(void* const* d_in, const int* in_sizes, int n_in,
                              void* d_out, int out_size, void* d_ws, size_t ws_size,
                              hipStream_t stream) {
    const float* x    = (const float*)d_in[0];
    const int*   ei   = (const int*)d_in[1];
    const float* ew   = (const float*)d_in[2];
    const int*   batch= (const int*)d_in[3];
    const float* W1   = (const float*)d_in[4];
    const float* b1   = (const float*)d_in[5];
    const float* W2   = (const float*)d_in[6];
    const float* b2   = (const float*)d_in[7];
    const float* W3   = (const float*)d_in[8];
    const float* b3   = (const float*)d_in[9];
    const float* Wm0  = (const float*)d_in[10];
    const float* bm0  = (const float*)d_in[11];
    const float* Wm1  = (const float*)d_in[12];
    const float* bm1  = (const float*)d_in[13];
    const float* Wout = (const float*)d_in[14];
    const float* bout = (const float*)d_in[15];
    float* out = (float*)d_out;

    // workspace: srn | sharedRegion(tre <-> tmpb+hA+hB) | scan bufs | dinv | rowptr | sums
    char* p = (char*)d_ws;
    int2*  srn = (int2*)p;               p += sizeof(int2) * (size_t)NE;      // 25.6 MB
    char*  S   = p;                      p += 12 * (size_t)NE;                // 38.4 MB shared
    int2*  tre = (int2*)S;
    unsigned short* tmpb = (unsigned short*)S;                                // 6.4 MB
    float* hA  = (float*)(S + 2 * (size_t)NN * HID);
    float* hB  = hA + (size_t)NN * HID;
    int*   cnt2    = (int*)p;            p += sizeof(int) * SCANL;
    int*   scanned = (int*)p;            p += sizeof(int) * SCANL;
    int*   bsum    = (int*)p;            p += sizeof(int) * 256;
    float* dinv    = (float*)p;          p += sizeof(float) * NN;
    int*   rowptr  = (int*)p;            p += sizeof(int) * NN;
    float* sums    = (float*)p;          p += sizeof(float) * NG * HID;
    float* counts  = (float*)p;

    dim3 blk(256);
    const int NB_SCAN = (SCANL + 1023) / 1024;  // 196
    const int NB_LIN = (NN + 63) / 64;          // 1563

    init_misc<<<9, blk, 0, stream>>>(sums);
    hist_bkt<<<NBLK, 1024, 0, stream>>>(ei, cnt2);
    scan_block<<<NB_SCAN, blk, 0, stream>>>(cnt2, scanned, bsum, SCANL);
    scan_top<<<1, 64, 0, stream>>>(bsum, NB_SCAN);
    scan_add<<<(SCANL + 255) / 256, blk, 0, stream>>>(scanned, bsum, SCANL);
    scatter_bkt<<<NBLK, 1024, 0, stream>>>(ei, ew, cnt2, scanned, tre);
    bucket_sort<<<NBKT, 512, 0, stream>>>(tre, scanned, srn, rowptr, dinv);
    finalize_wn<<<(NE / 2 + 255) / 256, blk, 0, stream>>>((int4*)srn, dinv);

    // layer 1
    linear_k<FIN, false><<<NB_LIN, blk, 0, stream>>>(x, W1, b1, dinv, tmpb, hA);
    aggregate<<<25000, blk, 0, stream>>>(srn, rowptr, dinv, tmpb, hA);
    // layer 2
    linear_k<HID, true><<<NB_LIN, blk, 0, stream>>>(hA, W2, b2, dinv, tmpb, hB);
    aggregate<<<25000, blk, 0, stream>>>(srn, rowptr, dinv, tmpb, hB);
    // layer 3
    linear_k<HID, true><<<NB_LIN, blk, 0, stream>>>(hB, W3, b3, dinv, tmpb, hA);
    aggregate<<<25000, blk, 0, stream>>>(srn, rowptr, dinv, tmpb, hA);

    pool_k<<<391, blk, 0, stream>>>(hA, batch, sums, counts);
    mlp_k<<<1, blk, 0, stream>>>(sums, counts, Wm0, bm0, Wm1, bm1, Wout, bout, out);
}

// Round 8
// 509.186 us; speedup vs baseline: 9.8716x; 1.0980x over previous
//
#include <hip/hip_runtime.h>

#define NN 100000
#define NE 3200000
#define FIN 128
#define HID 32
#define MH  64
#define NC  10
#define NG  64
#define NBKT 782           // ceil(NN/128) buckets of 128 dest nodes
#define NBLK 512           // edge-pass blocks
#define EPB  (NE / NBLK)   // 6250 edges per block
#define SCANL (NBKT * NBLK)
#define SRCMASK 0x1FFFF    // src < 100000 < 2^17
#define BCAP 5120          // bucket LDS capacity (mean 4092, sd ~64)

// fp32 -> bf16 bits, round-to-nearest-even
__device__ __forceinline__ unsigned short f32_to_bf16(float f) {
    unsigned int u = __float_as_uint(f);
    u += 0x7FFFu + ((u >> 16) & 1u);
    return (unsigned short)(u >> 16);
}

__global__ void init_misc(float* __restrict__ sc) {
    int i = blockIdx.x * 256 + threadIdx.x;
    if (i < NG * HID + NG) sc[i] = 0.0f;
}

// per-block LDS histogram over 782 dest-buckets; no global atomics
__global__ __launch_bounds__(1024)
void hist_bkt(const int* __restrict__ ei, int* __restrict__ cnt2) {
    __shared__ int h[NBKT];
    int tid = threadIdx.x, blk = blockIdx.x;
    for (int b = tid; b < NBKT; b += 1024) h[b] = 0;
    __syncthreads();
    int base = blk * EPB;
    for (int i = tid; i < EPB; i += 1024)
        atomicAdd(&h[ei[NE + base + i] >> 7], 1);
    __syncthreads();
    for (int b = tid; b < NBKT; b += 1024) cnt2[b * NBLK + blk] = h[b];
}

// ---- generic exclusive scan (1024 elems/block) ----
__global__ void scan_block(const int* __restrict__ in, int* __restrict__ out,
                           int* __restrict__ bsum, int n) {
    __shared__ int lds[256];
    int tid = threadIdx.x;
    int base = blockIdx.x * 1024 + tid * 4;
    int v0 = 0, v1 = 0, v2 = 0, v3 = 0;
    if (base + 0 < n) v0 = in[base + 0];
    if (base + 1 < n) v1 = in[base + 1];
    if (base + 2 < n) v2 = in[base + 2];
    if (base + 3 < n) v3 = in[base + 3];
    int s = v0 + v1 + v2 + v3;
    lds[tid] = s;
    __syncthreads();
    for (int off = 1; off < 256; off <<= 1) {
        int val = (tid >= off) ? lds[tid - off] : 0;
        __syncthreads();
        lds[tid] += val;
        __syncthreads();
    }
    int excl = lds[tid] - s;
    if (tid == 255) bsum[blockIdx.x] = lds[255];
    if (base + 0 < n) out[base + 0] = excl;
    if (base + 1 < n) out[base + 1] = excl + v0;
    if (base + 2 < n) out[base + 2] = excl + v0 + v1;
    if (base + 3 < n) out[base + 3] = excl + v0 + v1 + v2;
}

// wave-parallel exclusive scan of bsum (chunked shuffle scan with carry)
__global__ void scan_top(int* __restrict__ bsum, int nb) {
    int lane = threadIdx.x;  // 64 threads
    int carry = 0;
    for (int base = 0; base < nb; base += 64) {
        int i = base + lane;
        int orig = (i < nb) ? bsum[i] : 0;
        int v = orig;
#pragma unroll
        for (int off = 1; off < 64; off <<= 1) {
            int t = __shfl_up(v, off, 64);
            if (lane >= off) v += t;
        }
        if (i < nb) bsum[i] = carry + v - orig;   // exclusive
        carry += __shfl(v, 63, 64);
    }
}

__global__ void scan_add(int* __restrict__ data, const int* __restrict__ bsum, int n) {
    int i = blockIdx.x * 256 + threadIdx.x;
    if (i < n) data[i] += bsum[i >> 10];
}

// single global read: pack each edge into LDS at its sorted slot
// (pay.x = src | key7<<17 | bkt.lo8<<24 ; pay.y = ew bits with bkt.hi2 in
// the 2 lowest mantissa bits), then slot-major burst writes to tre.
__global__ __launch_bounds__(1024)
void scatter_bkt(const int* __restrict__ ei, const float* __restrict__ ew,
                 const int* __restrict__ cnt2, const int* __restrict__ scanned,
                 int2* __restrict__ tre) {
    __shared__ int2 pay[EPB];      // 50 KB
    __shared__ int scur[NBKT];     // scan workspace -> alloc cursor
    __shared__ int hexc[NBKT];
    __shared__ int gbase[NBKT];
    int tid = threadIdx.x, blk = blockIdx.x;
    int myh = 0;
    if (tid < NBKT) {
        myh = cnt2[tid * NBLK + blk];
        gbase[tid] = scanned[tid * NBLK + blk];
        scur[tid] = myh;
    }
    __syncthreads();
    for (int off = 1; off < NBKT; off <<= 1) {
        int v = (tid < NBKT && tid >= off) ? scur[tid - off] : 0;
        __syncthreads();
        if (tid < NBKT) scur[tid] += v;
        __syncthreads();
    }
    if (tid < NBKT) { int ex = scur[tid] - myh; hexc[tid] = ex; scur[tid] = ex; }
    __syncthreads();
    int base = blk * EPB;
    for (int i = tid; i < EPB; i += 1024) {
        int e = base + i;
        int c = ei[NE + e];
        int r = ei[e];
        unsigned int wb = __float_as_uint(ew[e]);
        int b = c >> 7;
        int j = atomicAdd(&scur[b], 1);
        pay[j] = make_int2(r | ((c & 127) << 17) | ((b & 0xFF) << 24),
                           (int)((wb & ~3u) | ((unsigned)b >> 8)));
    }
    __syncthreads();
    for (int j = tid; j < EPB; j += 1024) {
        int2 q = pay[j];
        int b = (int)((((unsigned)q.y & 3u) << 8) | (((unsigned)q.x >> 24) & 0xFFu));
        int pos = gbase[b] + (j - hexc[b]);
        tre[pos] = make_int2(q.x & 0x00FFFFFF, q.y & ~3);
    }
}

// one block per bucket: stage bucket edges in LDS (single global read),
// 128-bin count+scan, emit node-sorted (src, ew), rowptr, dinv
__global__ __launch_bounds__(512)
void bucket_sort(const int2* __restrict__ tre, const int* __restrict__ scanned,
                 int2* __restrict__ srn, int* __restrict__ rowptr,
                 float* __restrict__ dinv) {
    __shared__ int2 ed[BCAP];      // 40 KB
    __shared__ int h[128];
    __shared__ float dw[128];
    __shared__ int sc[128];
    __shared__ int cur[128];
    int b = blockIdx.x, tid = threadIdx.x;
    int base = scanned[b * NBLK];
    int end = (b == NBKT - 1) ? NE : scanned[(b + 1) * NBLK];
    int n = end - base;
    bool staged = (n <= BCAP);
    if (tid < 128) { h[tid] = 0; dw[tid] = 0.f; }
    if (staged)
        for (int i = tid; i < n; i += 512) ed[i] = tre[base + i];
    __syncthreads();
    for (int i = tid; i < n; i += 512) {
        int2 q = staged ? ed[i] : tre[base + i];
        int key = (q.x >> 17) & 127;
        atomicAdd(&h[key], 1);
        atomicAdd(&dw[key], __int_as_float(q.y));
    }
    __syncthreads();
    if (tid < 128) sc[tid] = h[tid];
    __syncthreads();
    for (int off = 1; off < 128; off <<= 1) {
        int v = (tid < 128 && tid >= off) ? sc[tid - off] : 0;
        __syncthreads();
        if (tid < 128) sc[tid] += v;
        __syncthreads();
    }
    if (tid < 128) {
        int node = b * 128 + tid;
        if (node < NN) {
            rowptr[node] = base + sc[tid];               // end offset
            dinv[node] = rsqrtf(1.0f + dw[tid]);         // self-loop included
        }
        cur[tid] = base + sc[tid] - h[tid];              // start cursor
    }
    __syncthreads();
    for (int i = tid; i < n; i += 512) {
        int2 q = staged ? ed[i] : tre[base + i];
        int key = (q.x >> 17) & 127;
        int pos = atomicAdd(&cur[key], 1);
        srn[pos] = make_int2(q.x & SRCMASK, q.y);
    }
}

// srn.y: ew -> ew * dinv[src]; 2 edges per thread via int4
__global__ void finalize_wn(int4* __restrict__ srn2, const float* __restrict__ dinv) {
    int t = blockIdx.x * 256 + threadIdx.x;
    if (t < NE / 2) {
        int4 q = srn2[t];
        q.y = __float_as_int(__int_as_float(q.y) * dinv[q.x]);
        q.w = __float_as_int(__int_as_float(q.w) * dinv[q.z]);
        srn2[t] = q;
    }
}

// LDS-tiled linear: 64-row x tile (padded, coalesced staging, relu folded),
// W pre-swizzled; thread = 2 rows x 4 cols, inner reads are ds_read_b128.
template <int IN_DIM, bool RELU_IN>
__global__ __launch_bounds__(256)
void linear_k(const float* __restrict__ in, const float* __restrict__ W,
              const float* __restrict__ bias, const float* __restrict__ dinv,
              unsigned short* __restrict__ tmpb, float* __restrict__ outi) {
    constexpr int J4 = IN_DIM / 4;       // 32 or 8
    constexpr int XSS = J4 + 1;          // padded row stride (float4)
    __shared__ float4 xs[64 * XSS];
    __shared__ float4 wp[IN_DIM * 8];
    int tid = threadIdx.x;
    for (int idx = tid; idx < IN_DIM * 8; idx += 256) {
        int j = idx >> 3, kg = idx & 7;
        const float* wr = W + j * 32 + kg;
        wp[idx] = make_float4(wr[0], wr[8], wr[16], wr[24]);
    }
    int rbase = blockIdx.x * 64;
    const float4* in4 = (const float4*)in;
    for (int idx = tid; idx < 64 * J4; idx += 256) {
        int row = idx / J4, j4 = idx % J4;
        int grow = rbase + row;
        float4 v = (grow < NN) ? in4[(size_t)grow * J4 + j4]
                               : make_float4(0.f, 0.f, 0.f, 0.f);
        if (RELU_IN) {
            v.x = fmaxf(v.x, 0.f); v.y = fmaxf(v.y, 0.f);
            v.z = fmaxf(v.z, 0.f); v.w = fmaxf(v.w, 0.f);
        }
        xs[row * XSS + j4] = v;
    }
    __syncthreads();
    int kg = tid & 7;          // cols kg + 8*kk
    int rp = tid >> 3;         // rows 2rp, 2rp+1
    int r0 = rbase + 2 * rp;
    if (r0 >= NN) return;
    const float4* x0 = &xs[(2 * rp) * XSS];
    const float4* x1 = &xs[(2 * rp + 1) * XSS];
    float a00 = 0, a01 = 0, a02 = 0, a03 = 0;
    float a10 = 0, a11 = 0, a12 = 0, a13 = 0;
#pragma unroll
    for (int j4 = 0; j4 < J4; ++j4) {
        float4 v0 = x0[j4], v1 = x1[j4];
        const float4* wj = &wp[j4 * 4 * 8 + kg];
        float4 w0 = wj[0], w1 = wj[8], w2 = wj[16], w3 = wj[24];
#define LSTEP(VX0, VX1, W4) \
        a00 = fmaf(VX0, W4.x, a00); a01 = fmaf(VX0, W4.y, a01); \
        a02 = fmaf(VX0, W4.z, a02); a03 = fmaf(VX0, W4.w, a03); \
        a10 = fmaf(VX1, W4.x, a10); a11 = fmaf(VX1, W4.y, a11); \
        a12 = fmaf(VX1, W4.z, a12); a13 = fmaf(VX1, W4.w, a13);
        LSTEP(v0.x, v1.x, w0)
        LSTEP(v0.y, v1.y, w1)
        LSTEP(v0.z, v1.z, w2)
        LSTEP(v0.w, v1.w, w3)
#undef LSTEP
    }
    float bk0 = bias[kg], bk1 = bias[kg + 8], bk2 = bias[kg + 16], bk3 = bias[kg + 24];
    float d0 = dinv[r0], d1 = dinv[r0 + 1];
    int o0 = r0 * HID + kg;
    int o1 = o0 + HID;
    tmpb[o0] = f32_to_bf16(a00); tmpb[o0 + 8] = f32_to_bf16(a01);
    tmpb[o0 + 16] = f32_to_bf16(a02); tmpb[o0 + 24] = f32_to_bf16(a03);
    tmpb[o1] = f32_to_bf16(a10); tmpb[o1 + 8] = f32_to_bf16(a11);
    tmpb[o1 + 16] = f32_to_bf16(a12); tmpb[o1 + 24] = f32_to_bf16(a13);
    float s0 = d0 * d0, s1 = d1 * d1;
    outi[o0] = bk0 + s0 * a00; outi[o0 + 8] = bk1 + s0 * a01;
    outi[o0 + 16] = bk2 + s0 * a02; outi[o0 + 24] = bk3 + s0 * a03;
    outi[o1] = bk0 + s1 * a10; outi[o1 + 8] = bk1 + s1 * a11;
    outi[o1 + 16] = bk2 + s1 * a12; outi[o1 + 24] = bk3 + s1 * a13;
}

// one wave per dest node: 64 lanes = 8 feat-quads x 8 edge slots.
__global__ void aggregate(const int2* __restrict__ srn, const int* __restrict__ rowptr,
                          const float* __restrict__ dinv,
                          const unsigned short* __restrict__ tmpb, float* __restrict__ h) {
    int wid = (blockIdx.x * 256 + threadIdx.x) >> 6;
    if (wid >= NN) return;
    int lane = threadIdx.x & 63;
    int g = lane >> 3;      // edge slot 0..7
    int q = lane & 7;       // feat quad (feats 4q..4q+3)
    int end = rowptr[wid];
    int start = (wid == 0) ? 0 : rowptr[wid - 1];
    float a0 = 0, a1 = 0, a2 = 0, a3 = 0;
    float b0 = 0, b1 = 0, b2 = 0, b3 = 0;
    int e = start + g;
    for (; e + 8 < end; e += 16) {
        int2 p0 = srn[e];
        int2 p1 = srn[e + 8];
        uint2 u0 = *(const uint2*)(tmpb + (size_t)p0.x * HID + 4 * q);
        uint2 u1 = *(const uint2*)(tmpb + (size_t)p1.x * HID + 4 * q);
        float w0 = __int_as_float(p0.y), w1 = __int_as_float(p1.y);
        a0 = fmaf(w0, __int_as_float((int)(u0.x << 16)), a0);
        a1 = fmaf(w0, __int_as_float((int)(u0.x & 0xFFFF0000u)), a1);
        a2 = fmaf(w0, __int_as_float((int)(u0.y << 16)), a2);
        a3 = fmaf(w0, __int_as_float((int)(u0.y & 0xFFFF0000u)), a3);
        b0 = fmaf(w1, __int_as_float((int)(u1.x << 16)), b0);
        b1 = fmaf(w1, __int_as_float((int)(u1.x & 0xFFFF0000u)), b1);
        b2 = fmaf(w1, __int_as_float((int)(u1.y << 16)), b2);
        b3 = fmaf(w1, __int_as_float((int)(u1.y & 0xFFFF0000u)), b3);
    }
    if (e < end) {
        int2 p = srn[e];
        uint2 u = *(const uint2*)(tmpb + (size_t)p.x * HID + 4 * q);
        float w = __int_as_float(p.y);
        a0 = fmaf(w, __int_as_float((int)(u.x << 16)), a0);
        a1 = fmaf(w, __int_as_float((int)(u.x & 0xFFFF0000u)), a1);
        a2 = fmaf(w, __int_as_float((int)(u.y << 16)), a2);
        a3 = fmaf(w, __int_as_float((int)(u.y & 0xFFFF0000u)), a3);
    }
    a0 += b0; a1 += b1; a2 += b2; a3 += b3;
    a0 += __shfl_xor(a0, 8, 64); a1 += __shfl_xor(a1, 8, 64);
    a2 += __shfl_xor(a2, 8, 64); a3 += __shfl_xor(a3, 8, 64);
    a0 += __shfl_xor(a0, 16, 64); a1 += __shfl_xor(a1, 16, 64);
    a2 += __shfl_xor(a2, 16, 64); a3 += __shfl_xor(a3, 16, 64);
    a0 += __shfl_xor(a0, 32, 64); a1 += __shfl_xor(a1, 32, 64);
    a2 += __shfl_xor(a2, 32, 64); a3 += __shfl_xor(a3, 32, 64);
    if (g == 0) {
        float d = dinv[wid];
        float4* hp = (float4*)(h + (size_t)wid * HID);
        float4 o = hp[q];
        o.x += d * a0; o.y += d * a1; o.z += d * a2; o.w += d * a3;
        hp[q] = o;
    }
}

// sorted-batch run-length pooling
__global__ void pool_k(const float* __restrict__ h, const int* __restrict__ batch,
                       float* __restrict__ sums, float* __restrict__ counts) {
    int t = blockIdx.x * 256 + threadIdx.x;
    int chunk = t >> 5, k = t & 31;
    int n0 = chunk * 32;
    if (n0 >= NN) return;
    int n1 = min(n0 + 32, NN);
    int g = batch[n0];
    float acc = 0.f, cacc = 0.f;
    for (int i = n0; i < n1; ++i) {
        int gi = batch[i];
        if (gi != g) {
            atomicAdd(&sums[g * HID + k], acc);
            if (k == 0) atomicAdd(&counts[g], cacc);
            g = gi; acc = 0.f; cacc = 0.f;
        }
        acc += h[(size_t)i * HID + k];
        cacc += 1.f;
    }
    atomicAdd(&sums[g * HID + k], acc);
    if (k == 0) atomicAdd(&counts[g], cacc);
}

// whole MLP in one block
__global__ void mlp_k(const float* __restrict__ sums, const float* __restrict__ counts,
                      const float* __restrict__ Wm0, const float* __restrict__ bm0,
                      const float* __restrict__ Wm1, const float* __restrict__ bm1,
                      const float* __restrict__ Wout, const float* __restrict__ bout,
                      float* __restrict__ out) {
    __shared__ float g0[NG * HID];
    __shared__ float g1[NG * MH];
    __shared__ float g2[NG * MH];
    int tid = threadIdx.x;
    for (int idx = tid; idx < NG * HID; idx += 256) {
        int g = idx / HID;
        g0[idx] = sums[idx] / fmaxf(counts[g], 1.0f);
    }
    __syncthreads();
    for (int idx = tid; idx < NG * MH; idx += 256) {
        int g = idx / MH, k = idx % MH;
        float acc = bm0[k];
        for (int j = 0; j < HID; ++j) acc = fmaf(g0[g * HID + j], Wm0[j * MH + k], acc);
        g1[idx] = fmaxf(acc, 0.f);
    }
    __syncthreads();
    for (int idx = tid; idx < NG * MH; idx += 256) {
        int g = idx / MH, k = idx % MH;
        float acc = bm1[k];
        for (int j = 0; j < MH; ++j) acc = fmaf(g1[g * MH + j], Wm1[j * MH + k], acc);
        g2[idx] = fmaxf(acc, 0.f);
    }
    __syncthreads();
    for (int idx = tid; idx < NG * NC; idx += 256) {
        int g = idx / NC, k = idx % NC;
        float acc = bout[k];
        for (int j = 0; j < MH; ++j) acc = fmaf(g2[g * MH + j], Wout[j * NC + k], acc);
        out[idx] = acc;
    }
}

extern "C" void kernel_launch(void* const* d_in, const int* in_sizes, int n_in,
                              void* d_out, int out_size, void* d_ws, size_t ws_size,
                              hipStream_t stream) {
    const float* x    = (const float*)d_in[0];
    const int*   ei   = (const int*)d_in[1];
    const float* ew   = (const float*)d_in[2];
    const int*   batch= (const int*)d_in[3];
    const float* W1   = (const float*)d_in[4];
    const float* b1   = (const float*)d_in[5];
    const float* W2   = (const float*)d_in[6];
    const float* b2   = (const float*)d_in[7];
    const float* W3   = (const float*)d_in[8];
    const float* b3   = (const float*)d_in[9];
    const float* Wm0  = (const float*)d_in[10];
    const float* bm0  = (const float*)d_in[11];
    const float* Wm1  = (const float*)d_in[12];
    const float* bm1  = (const float*)d_in[13];
    const float* Wout = (const float*)d_in[14];
    const float* bout = (const float*)d_in[15];
    float* out = (float*)d_out;

    // workspace: srn | S (tre+cnt2+scanned <-> tmpb+hA+hB) | small bufs
    char* p = (char*)d_ws;
    int2*  srn = (int2*)p;               p += sizeof(int2) * (size_t)NE;      // 25.6 MB
    char*  S   = p;                      p += 12 * (size_t)NE;                // 38.4 MB shared
    int2*  tre = (int2*)S;                                                    // 25.6 MB
    int*   cnt2    = (int*)(S + sizeof(int2) * (size_t)NE);                   // 1.6 MB (dies pre-layer1)
    int*   scanned = cnt2 + SCANL;                                            // 1.6 MB
    unsigned short* tmpb = (unsigned short*)S;                                // 6.4 MB
    float* hA  = (float*)(S + 2 * (size_t)NN * HID);
    float* hB  = hA + (size_t)NN * HID;
    int*   bsum    = (int*)p;            p += sizeof(int) * 512;
    float* dinv    = (float*)p;          p += sizeof(float) * NN;
    int*   rowptr  = (int*)p;            p += sizeof(int) * NN;
    float* sums    = (float*)p;          p += sizeof(float) * NG * HID;
    float* counts  = (float*)p;

    dim3 blk(256);
    const int NB_SCAN = (SCANL + 1023) / 1024;  // 391
    const int NB_LIN = (NN + 63) / 64;          // 1563

    init_misc<<<9, blk, 0, stream>>>(sums);
    hist_bkt<<<NBLK, 1024, 0, stream>>>(ei, cnt2);
    scan_block<<<NB_SCAN, blk, 0, stream>>>(cnt2, scanned, bsum, SCANL);
    scan_top<<<1, 64, 0, stream>>>(bsum, NB_SCAN);
    scan_add<<<(SCANL + 255) / 256, blk, 0, stream>>>(scanned, bsum, SCANL);
    scatter_bkt<<<NBLK, 1024, 0, stream>>>(ei, ew, cnt2, scanned, tre);
    bucket_sort<<<NBKT, 512, 0, stream>>>(tre, scanned, srn, rowptr, dinv);
    finalize_wn<<<(NE / 2 + 255) / 256, blk, 0, stream>>>((int4*)srn, dinv);

    // layer 1
    linear_k<FIN, false><<<NB_LIN, blk, 0, stream>>>(x, W1, b1, dinv, tmpb, hA);
    aggregate<<<25000, blk, 0, stream>>>(srn, rowptr, dinv, tmpb, hA);
    // layer 2
    linear_k<HID, true><<<NB_LIN, blk, 0, stream>>>(hA, W2, b2, dinv, tmpb, hB);
    aggregate<<<25000, blk, 0, stream>>>(srn, rowptr, dinv, tmpb, hB);
    // layer 3
    linear_k<HID, true><<<NB_LIN, blk, 0, stream>>>(hB, W3, b3, dinv, tmpb, hA);
    aggregate<<<25000, blk, 0, stream>>>(srn, rowptr, dinv, tmpb, hA);

    pool_k<<<391, blk, 0, stream>>>(hA, batch, sums, counts);
    mlp_k<<<1, blk, 0, stream>>>(sums, counts, Wm0, bm0, Wm1, bm1, Wout, bout, out);
}

// Round 9
// 486.952 us; speedup vs baseline: 10.3224x; 1.0457x over previous
//
#include <hip/hip_runtime.h>

#define NN 100000
#define NE 3200000
#define FIN 128
#define HID 32
#define MH  64
#define NC  10
#define NG  64
#define NBKT 782           // ceil(NN/128) buckets of 128 dest nodes
#define NBLK 512           // edge-pass blocks
#define EPB  (NE / NBLK)   // 6250 edges per block
#define SCANL (NBKT * NBLK)
#define SRCMASK 0x1FFFF    // src < 100000 < 2^17
#define BCAP 5120          // bucket LDS capacity (mean 4092, sd ~64)

// fp32 -> bf16 bits, round-to-nearest-even
__device__ __forceinline__ unsigned short f32_to_bf16(float f) {
    unsigned int u = __float_as_uint(f);
    u += 0x7FFFu + ((u >> 16) & 1u);
    return (unsigned short)(u >> 16);
}

__global__ void init_misc(float* __restrict__ sc) {
    int i = blockIdx.x * 256 + threadIdx.x;
    if (i < NG * HID + NG) sc[i] = 0.0f;
}

// per-block LDS histogram over 782 dest-buckets; no global atomics
__global__ __launch_bounds__(1024)
void hist_bkt(const int* __restrict__ ei, int* __restrict__ cnt2) {
    __shared__ int h[NBKT];
    int tid = threadIdx.x, blk = blockIdx.x;
    for (int b = tid; b < NBKT; b += 1024) h[b] = 0;
    __syncthreads();
    int base = blk * EPB;
    for (int i = tid; i < EPB; i += 1024)
        atomicAdd(&h[ei[NE + base + i] >> 7], 1);
    __syncthreads();
    for (int b = tid; b < NBKT; b += 1024) cnt2[b * NBLK + blk] = h[b];
}

// ---- generic exclusive scan (1024 elems/block) ----
__global__ void scan_block(const int* __restrict__ in, int* __restrict__ out,
                           int* __restrict__ bsum, int n) {
    __shared__ int lds[256];
    int tid = threadIdx.x;
    int base = blockIdx.x * 1024 + tid * 4;
    int v0 = 0, v1 = 0, v2 = 0, v3 = 0;
    if (base + 0 < n) v0 = in[base + 0];
    if (base + 1 < n) v1 = in[base + 1];
    if (base + 2 < n) v2 = in[base + 2];
    if (base + 3 < n) v3 = in[base + 3];
    int s = v0 + v1 + v2 + v3;
    lds[tid] = s;
    __syncthreads();
    for (int off = 1; off < 256; off <<= 1) {
        int val = (tid >= off) ? lds[tid - off] : 0;
        __syncthreads();
        lds[tid] += val;
        __syncthreads();
    }
    int excl = lds[tid] - s;
    if (tid == 255) bsum[blockIdx.x] = lds[255];
    if (base + 0 < n) out[base + 0] = excl;
    if (base + 1 < n) out[base + 1] = excl + v0;
    if (base + 2 < n) out[base + 2] = excl + v0 + v1;
    if (base + 3 < n) out[base + 3] = excl + v0 + v1 + v2;
}

// wave-parallel exclusive scan of bsum (chunked shuffle scan with carry)
__global__ void scan_top(int* __restrict__ bsum, int nb) {
    int lane = threadIdx.x;  // 64 threads
    int carry = 0;
    for (int base = 0; base < nb; base += 64) {
        int i = base + lane;
        int orig = (i < nb) ? bsum[i] : 0;
        int v = orig;
#pragma unroll
        for (int off = 1; off < 64; off <<= 1) {
            int t = __shfl_up(v, off, 64);
            if (lane >= off) v += t;
        }
        if (i < nb) bsum[i] = carry + v - orig;   // exclusive
        carry += __shfl(v, 63, 64);
    }
}

__global__ void scan_add(int* __restrict__ data, const int* __restrict__ bsum, int n) {
    int i = blockIdx.x * 256 + threadIdx.x;
    if (i < n) data[i] += bsum[i >> 10];
}

// single global read: pack each edge into LDS at its sorted slot, then
// slot-major burst writes to tre.
__global__ __launch_bounds__(1024)
void scatter_bkt(const int* __restrict__ ei, const float* __restrict__ ew,
                 const int* __restrict__ cnt2, const int* __restrict__ scanned,
                 int2* __restrict__ tre) {
    __shared__ int2 pay[EPB];      // 50 KB
    __shared__ int scur[NBKT];
    __shared__ int hexc[NBKT];
    __shared__ int gbase[NBKT];
    int tid = threadIdx.x, blk = blockIdx.x;
    int myh = 0;
    if (tid < NBKT) {
        myh = cnt2[tid * NBLK + blk];
        gbase[tid] = scanned[tid * NBLK + blk];
        scur[tid] = myh;
    }
    __syncthreads();
    for (int off = 1; off < NBKT; off <<= 1) {
        int v = (tid < NBKT && tid >= off) ? scur[tid - off] : 0;
        __syncthreads();
        if (tid < NBKT) scur[tid] += v;
        __syncthreads();
    }
    if (tid < NBKT) { int ex = scur[tid] - myh; hexc[tid] = ex; scur[tid] = ex; }
    __syncthreads();
    int base = blk * EPB;
    for (int i = tid; i < EPB; i += 1024) {
        int e = base + i;
        int c = ei[NE + e];
        int r = ei[e];
        unsigned int wb = __float_as_uint(ew[e]);
        int b = c >> 7;
        int j = atomicAdd(&scur[b], 1);
        pay[j] = make_int2(r | ((c & 127) << 17) | ((b & 0xFF) << 24),
                           (int)((wb & ~3u) | ((unsigned)b >> 8)));
    }
    __syncthreads();
    for (int j = tid; j < EPB; j += 1024) {
        int2 q = pay[j];
        int b = (int)((((unsigned)q.y & 3u) << 8) | (((unsigned)q.x >> 24) & 0xFFu));
        int pos = gbase[b] + (j - hexc[b]);
        tre[pos] = make_int2(q.x & 0x00FFFFFF, q.y & ~3);
    }
}

// per bucket: stream tre, LDS-accumulate weighted in-degree, write dinv
__global__ __launch_bounds__(512)
void deg_k(const int2* __restrict__ tre, const int* __restrict__ scanned,
           float* __restrict__ dinv) {
    __shared__ float dw[128];
    int b = blockIdx.x, tid = threadIdx.x;
    int base = scanned[b * NBLK];
    int end = (b == NBKT - 1) ? NE : scanned[(b + 1) * NBLK];
    if (tid < 128) dw[tid] = 0.f;
    __syncthreads();
    for (int i = base + tid; i < end; i += 512) {
        int2 q = tre[i];
        atomicAdd(&dw[(q.x >> 17) & 127], __int_as_float(q.y));
    }
    __syncthreads();
    if (tid < 128) {
        int node = b * 128 + tid;
        if (node < NN) dinv[node] = rsqrtf(1.0f + dw[tid]);
    }
}

// per bucket: stage in LDS, 128-bin count+scan, emit node-sorted 4B packed
// edges: src(17b) | sign-free bf16 of (ew*dinv[src]) (15b). Also rowptr.
__global__ __launch_bounds__(512)
void sort_k(const int2* __restrict__ tre, const int* __restrict__ scanned,
            const float* __restrict__ dinv,
            unsigned int* __restrict__ srn4, int* __restrict__ rowptr) {
    __shared__ int2 ed[BCAP];      // 40 KB
    __shared__ int h[128];
    __shared__ int sc[128];
    __shared__ int cur[128];
    int b = blockIdx.x, tid = threadIdx.x;
    int base = scanned[b * NBLK];
    int end = (b == NBKT - 1) ? NE : scanned[(b + 1) * NBLK];
    int n = end - base;
    bool staged = (n <= BCAP);
    if (tid < 128) h[tid] = 0;
    if (staged)
        for (int i = tid; i < n; i += 512) ed[i] = tre[base + i];
    __syncthreads();
    for (int i = tid; i < n; i += 512) {
        int2 q = staged ? ed[i] : tre[base + i];
        atomicAdd(&h[(q.x >> 17) & 127], 1);
    }
    __syncthreads();
    if (tid < 128) sc[tid] = h[tid];
    __syncthreads();
    for (int off = 1; off < 128; off <<= 1) {
        int v = (tid < 128 && tid >= off) ? sc[tid - off] : 0;
        __syncthreads();
        if (tid < 128) sc[tid] += v;
        __syncthreads();
    }
    if (tid < 128) {
        int node = b * 128 + tid;
        if (node < NN) rowptr[node] = base + sc[tid];     // end offset
        cur[tid] = base + sc[tid] - h[tid];               // start cursor
    }
    __syncthreads();
    for (int i = tid; i < n; i += 512) {
        int2 q = staged ? ed[i] : tre[base + i];
        int key = (q.x >> 17) & 127;
        int pos = atomicAdd(&cur[key], 1);
        unsigned int src = (unsigned)(q.x & SRCMASK);
        float w = __int_as_float(q.y) * dinv[src];
        unsigned int wb = __float_as_uint(w);
        wb += 0x7FFFu + ((wb >> 16) & 1u);               // RNE to bf16
        srn4[pos] = src | (((wb >> 16) & 0x7FFFu) << 17);
    }
}

// LDS-tiled linear: 64-row x tile (padded, coalesced staging, relu folded),
// W pre-swizzled; thread = 2 rows x 4 cols, inner reads are ds_read_b128.
// Writes ONLY tmpb (bf16); bias/self-loop handled in aggregate's epilogue.
template <int IN_DIM, bool RELU_IN>
__global__ __launch_bounds__(256)
void linear_k(const float* __restrict__ in, const float* __restrict__ W,
              unsigned short* __restrict__ tmpb) {
    constexpr int J4 = IN_DIM / 4;       // 32 or 8
    constexpr int XSS = J4 + 1;          // padded row stride (float4)
    __shared__ float4 xs[64 * XSS];
    __shared__ float4 wp[IN_DIM * 8];
    int tid = threadIdx.x;
    for (int idx = tid; idx < IN_DIM * 8; idx += 256) {
        int j = idx >> 3, kg = idx & 7;
        const float* wr = W + j * 32 + kg;
        wp[idx] = make_float4(wr[0], wr[8], wr[16], wr[24]);
    }
    int rbase = blockIdx.x * 64;
    const float4* in4 = (const float4*)in;
    for (int idx = tid; idx < 64 * J4; idx += 256) {
        int row = idx / J4, j4 = idx % J4;
        int grow = rbase + row;
        float4 v = (grow < NN) ? in4[(size_t)grow * J4 + j4]
                               : make_float4(0.f, 0.f, 0.f, 0.f);
        if (RELU_IN) {
            v.x = fmaxf(v.x, 0.f); v.y = fmaxf(v.y, 0.f);
            v.z = fmaxf(v.z, 0.f); v.w = fmaxf(v.w, 0.f);
        }
        xs[row * XSS + j4] = v;
    }
    __syncthreads();
    int kg = tid & 7;          // cols kg + 8*kk
    int rp = tid >> 3;         // rows 2rp, 2rp+1
    int r0 = rbase + 2 * rp;
    if (r0 >= NN) return;
    const float4* x0 = &xs[(2 * rp) * XSS];
    const float4* x1 = &xs[(2 * rp + 1) * XSS];
    float a00 = 0, a01 = 0, a02 = 0, a03 = 0;
    float a10 = 0, a11 = 0, a12 = 0, a13 = 0;
#pragma unroll
    for (int j4 = 0; j4 < J4; ++j4) {
        float4 v0 = x0[j4], v1 = x1[j4];
        const float4* wj = &wp[j4 * 4 * 8 + kg];
        float4 w0 = wj[0], w1 = wj[8], w2 = wj[16], w3 = wj[24];
#define LSTEP(VX0, VX1, W4) \
        a00 = fmaf(VX0, W4.x, a00); a01 = fmaf(VX0, W4.y, a01); \
        a02 = fmaf(VX0, W4.z, a02); a03 = fmaf(VX0, W4.w, a03); \
        a10 = fmaf(VX1, W4.x, a10); a11 = fmaf(VX1, W4.y, a11); \
        a12 = fmaf(VX1, W4.z, a12); a13 = fmaf(VX1, W4.w, a13);
        LSTEP(v0.x, v1.x, w0)
        LSTEP(v0.y, v1.y, w1)
        LSTEP(v0.z, v1.z, w2)
        LSTEP(v0.w, v1.w, w3)
#undef LSTEP
    }
    int o0 = r0 * HID + kg;
    int o1 = o0 + HID;
    tmpb[o0] = f32_to_bf16(a00); tmpb[o0 + 8] = f32_to_bf16(a01);
    tmpb[o0 + 16] = f32_to_bf16(a02); tmpb[o0 + 24] = f32_to_bf16(a03);
    tmpb[o1] = f32_to_bf16(a10); tmpb[o1 + 8] = f32_to_bf16(a11);
    tmpb[o1 + 16] = f32_to_bf16(a12); tmpb[o1 + 24] = f32_to_bf16(a13);
}

// one wave per dest node: 64 lanes = 8 feat-quads x 8 edge slots.
// h = bias + dinv^2*self + dinv * sum(w*msg); write-only output.
__global__ void aggregate(const unsigned int* __restrict__ srn4,
                          const int* __restrict__ rowptr,
                          const float* __restrict__ dinv,
                          const float* __restrict__ bias,
                          const unsigned short* __restrict__ tmpb,
                          float* __restrict__ h) {
    int wid = (blockIdx.x * 256 + threadIdx.x) >> 6;
    if (wid >= NN) return;
    int lane = threadIdx.x & 63;
    int g = lane >> 3;      // edge slot 0..7
    int q = lane & 7;       // feat quad (feats 4q..4q+3)
    int end = rowptr[wid];
    int start = (wid == 0) ? 0 : rowptr[wid - 1];
    float a0 = 0, a1 = 0, a2 = 0, a3 = 0;
    float b0 = 0, b1 = 0, b2 = 0, b3 = 0;
    int e = start + g;
    for (; e + 8 < end; e += 16) {
        unsigned int p0 = srn4[e];
        unsigned int p1 = srn4[e + 8];
        uint2 u0 = *(const uint2*)(tmpb + (size_t)(p0 & SRCMASK) * HID + 4 * q);
        uint2 u1 = *(const uint2*)(tmpb + (size_t)(p1 & SRCMASK) * HID + 4 * q);
        float w0 = __uint_as_float((p0 >> 1) & 0x7FFF0000u);
        float w1 = __uint_as_float((p1 >> 1) & 0x7FFF0000u);
        a0 = fmaf(w0, __int_as_float((int)(u0.x << 16)), a0);
        a1 = fmaf(w0, __int_as_float((int)(u0.x & 0xFFFF0000u)), a1);
        a2 = fmaf(w0, __int_as_float((int)(u0.y << 16)), a2);
        a3 = fmaf(w0, __int_as_float((int)(u0.y & 0xFFFF0000u)), a3);
        b0 = fmaf(w1, __int_as_float((int)(u1.x << 16)), b0);
        b1 = fmaf(w1, __int_as_float((int)(u1.x & 0xFFFF0000u)), b1);
        b2 = fmaf(w1, __int_as_float((int)(u1.y << 16)), b2);
        b3 = fmaf(w1, __int_as_float((int)(u1.y & 0xFFFF0000u)), b3);
    }
    if (e < end) {
        unsigned int p = srn4[e];
        uint2 u = *(const uint2*)(tmpb + (size_t)(p & SRCMASK) * HID + 4 * q);
        float w = __uint_as_float((p >> 1) & 0x7FFF0000u);
        a0 = fmaf(w, __int_as_float((int)(u.x << 16)), a0);
        a1 = fmaf(w, __int_as_float((int)(u.x & 0xFFFF0000u)), a1);
        a2 = fmaf(w, __int_as_float((int)(u.y << 16)), a2);
        a3 = fmaf(w, __int_as_float((int)(u.y & 0xFFFF0000u)), a3);
    }
    a0 += b0; a1 += b1; a2 += b2; a3 += b3;
    a0 += __shfl_xor(a0, 8, 64); a1 += __shfl_xor(a1, 8, 64);
    a2 += __shfl_xor(a2, 8, 64); a3 += __shfl_xor(a3, 8, 64);
    a0 += __shfl_xor(a0, 16, 64); a1 += __shfl_xor(a1, 16, 64);
    a2 += __shfl_xor(a2, 16, 64); a3 += __shfl_xor(a3, 16, 64);
    a0 += __shfl_xor(a0, 32, 64); a1 += __shfl_xor(a1, 32, 64);
    a2 += __shfl_xor(a2, 32, 64); a3 += __shfl_xor(a3, 32, 64);
    if (g == 0) {
        float d = dinv[wid];
        float d2 = d * d;
        uint2 sv = *(const uint2*)(tmpb + (size_t)wid * HID + 4 * q);
        float4 bq = ((const float4*)bias)[q];
        float s0 = __int_as_float((int)(sv.x << 16));
        float s1 = __int_as_float((int)(sv.x & 0xFFFF0000u));
        float s2 = __int_as_float((int)(sv.y << 16));
        float s3 = __int_as_float((int)(sv.y & 0xFFFF0000u));
        float4 o;
        o.x = bq.x + d2 * s0 + d * a0;
        o.y = bq.y + d2 * s1 + d * a1;
        o.z = bq.z + d2 * s2 + d * a2;
        o.w = bq.w + d2 * s3 + d * a3;
        ((float4*)(h + (size_t)wid * HID))[q] = o;
    }
}

// sorted-batch run-length pooling
__global__ void pool_k(const float* __restrict__ h, const int* __restrict__ batch,
                       float* __restrict__ sums, float* __restrict__ counts) {
    int t = blockIdx.x * 256 + threadIdx.x;
    int chunk = t >> 5, k = t & 31;
    int n0 = chunk * 32;
    if (n0 >= NN) return;
    int n1 = min(n0 + 32, NN);
    int g = batch[n0];
    float acc = 0.f, cacc = 0.f;
    for (int i = n0; i < n1; ++i) {
        int gi = batch[i];
        if (gi != g) {
            atomicAdd(&sums[g * HID + k], acc);
            if (k == 0) atomicAdd(&counts[g], cacc);
            g = gi; acc = 0.f; cacc = 0.f;
        }
        acc += h[(size_t)i * HID + k];
        cacc += 1.f;
    }
    atomicAdd(&sums[g * HID + k], acc);
    if (k == 0) atomicAdd(&counts[g], cacc);
}

// whole MLP in one block
__global__ void mlp_k(const float* __restrict__ sums, const float* __restrict__ counts,
                      const float* __restrict__ Wm0, const float* __restrict__ bm0,
                      const float* __restrict__ Wm1, const float* __restrict__ bm1,
                      const float* __restrict__ Wout, const float* __restrict__ bout,
                      float* __restrict__ out) {
    __shared__ float g0[NG * HID];
    __shared__ float g1[NG * MH];
    __shared__ float g2[NG * MH];
    int tid = threadIdx.x;
    for (int idx = tid; idx < NG * HID; idx += 256) {
        int g = idx / HID;
        g0[idx] = sums[idx] / fmaxf(counts[g], 1.0f);
    }
    __syncthreads();
    for (int idx = tid; idx < NG * MH; idx += 256) {
        int g = idx / MH, k = idx % MH;
        float acc = bm0[k];
        for (int j = 0; j < HID; ++j) acc = fmaf(g0[g * HID + j], Wm0[j * MH + k], acc);
        g1[idx] = fmaxf(acc, 0.f);
    }
    __syncthreads();
    for (int idx = tid; idx < NG * MH; idx += 256) {
        int g = idx / MH, k = idx % MH;
        float acc = bm1[k];
        for (int j = 0; j < MH; ++j) acc = fmaf(g1[g * MH + j], Wm1[j * MH + k], acc);
        g2[idx] = fmaxf(acc, 0.f);
    }
    __syncthreads();
    for (int idx = tid; idx < NG * NC; idx += 256) {
        int g = idx / NC, k = idx % NC;
        float acc = bout[k];
        for (int j = 0; j < MH; ++j) acc = fmaf(g2[g * MH + j], Wout[j * NC + k], acc);
        out[idx] = acc;
    }
}

extern "C" void kernel_launch(void* const* d_in, const int* in_sizes, int n_in,
                              void* d_out, int out_size, void* d_ws, size_t ws_size,
                              hipStream_t stream) {
    const float* x    = (const float*)d_in[0];
    const int*   ei   = (const int*)d_in[1];
    const float* ew   = (const float*)d_in[2];
    const int*   batch= (const int*)d_in[3];
    const float* W1   = (const float*)d_in[4];
    const float* b1   = (const float*)d_in[5];
    const float* W2   = (const float*)d_in[6];
    const float* b2   = (const float*)d_in[7];
    const float* W3   = (const float*)d_in[8];
    const float* b3   = (const float*)d_in[9];
    const float* Wm0  = (const float*)d_in[10];
    const float* bm0  = (const float*)d_in[11];
    const float* Wm1  = (const float*)d_in[12];
    const float* bm1  = (const float*)d_in[13];
    const float* Wout = (const float*)d_in[14];
    const float* bout = (const float*)d_in[15];
    float* out = (float*)d_out;

    // workspace: srn4 | S (tre+cnt2+scanned <-> tmpb+hA+hB) | small bufs
    char* p = (char*)d_ws;
    unsigned int* srn4 = (unsigned int*)p; p += sizeof(unsigned int) * (size_t)NE; // 12.8 MB
    char*  S   = p;                      p += 12 * (size_t)NE;                // 38.4 MB shared
    int2*  tre = (int2*)S;                                                    // 25.6 MB
    int*   cnt2    = (int*)(S + sizeof(int2) * (size_t)NE);                   // 1.6 MB (dies pre-layer1)
    int*   scanned = cnt2 + SCANL;                                            // 1.6 MB
    unsigned short* tmpb = (unsigned short*)S;                                // 6.4 MB
    float* hA  = (float*)(S + 2 * (size_t)NN * HID);
    float* hB  = hA + (size_t)NN * HID;
    int*   bsum    = (int*)p;            p += sizeof(int) * 512;
    float* dinv    = (float*)p;          p += sizeof(float) * NN;
    int*   rowptr  = (int*)p;            p += sizeof(int) * NN;
    float* sums    = (float*)p;          p += sizeof(float) * NG * HID;
    float* counts  = (float*)p;

    dim3 blk(256);
    const int NB_SCAN = (SCANL + 1023) / 1024;  // 391
    const int NB_LIN = (NN + 63) / 64;          // 1563

    init_misc<<<9, blk, 0, stream>>>(sums);
    hist_bkt<<<NBLK, 1024, 0, stream>>>(ei, cnt2);
    scan_block<<<NB_SCAN, blk, 0, stream>>>(cnt2, scanned, bsum, SCANL);
    scan_top<<<1, 64, 0, stream>>>(bsum, NB_SCAN);
    scan_add<<<(SCANL + 255) / 256, blk, 0, stream>>>(scanned, bsum, SCANL);
    scatter_bkt<<<NBLK, 1024, 0, stream>>>(ei, ew, cnt2, scanned, tre);
    deg_k<<<NBKT, 512, 0, stream>>>(tre, scanned, dinv);
    sort_k<<<NBKT, 512, 0, stream>>>(tre, scanned, dinv, srn4, rowptr);

    // layer 1
    linear_k<FIN, false><<<NB_LIN, blk, 0, stream>>>(x, W1, tmpb);
    aggregate<<<25000, blk, 0, stream>>>(srn4, rowptr, dinv, b1, tmpb, hA);
    // layer 2
    linear_k<HID, true><<<NB_LIN, blk, 0, stream>>>(hA, W2, tmpb);
    aggregate<<<25000, blk, 0, stream>>>(srn4, rowptr, dinv, b2, tmpb, hB);
    // layer 3
    linear_k<HID, true><<<NB_LIN, blk, 0, stream>>>(hB, W3, tmpb);
    aggregate<<<25000, blk, 0, stream>>>(srn4, rowptr, dinv, b3, tmpb, hA);

    pool_k<<<391, blk, 0, stream>>>(hA, batch, sums, counts);
    mlp_k<<<1, blk, 0, stream>>>(sums, counts, Wm0, bm0, Wm1, bm1, Wout, bout, out);
}

// Round 10
// 460.978 us; speedup vs baseline: 10.9040x; 1.0563x over previous
//
#include <hip/hip_runtime.h>

#define NN 100000
#define NE 3200000
#define FIN 128
#define HID 32
#define MH  64
#define NC  10
#define NG  64
#define NBKT 782           // ceil(NN/128) buckets of 128 dest nodes
#define NBLK 512           // edge-pass blocks
#define EPB  (NE / NBLK)   // 6250 edges per block
#define SCANL (NBKT * NBLK)
#define SRCMASK 0x1FFFF    // src < 100000 < 2^17
#define BCAP 5120          // bucket LDS capacity (mean 4092, sd ~64)

typedef float floatx2 __attribute__((ext_vector_type(2)));

__global__ void init_misc(float* __restrict__ sc) {
    int i = blockIdx.x * 256 + threadIdx.x;
    if (i < NG * HID + NG) sc[i] = 0.0f;
}

// per-block LDS histogram over 782 dest-buckets; no global atomics
__global__ __launch_bounds__(1024)
void hist_bkt(const int* __restrict__ ei, int* __restrict__ cnt2) {
    __shared__ int h[NBKT];
    int tid = threadIdx.x, blk = blockIdx.x;
    for (int b = tid; b < NBKT; b += 1024) h[b] = 0;
    __syncthreads();
    int base = blk * EPB;
    for (int i = tid; i < EPB; i += 1024)
        atomicAdd(&h[ei[NE + base + i] >> 7], 1);
    __syncthreads();
    for (int b = tid; b < NBKT; b += 1024) cnt2[b * NBLK + blk] = h[b];
}

// ---- generic exclusive scan (1024 elems/block) ----
__global__ void scan_block(const int* __restrict__ in, int* __restrict__ out,
                           int* __restrict__ bsum, int n) {
    __shared__ int lds[256];
    int tid = threadIdx.x;
    int base = blockIdx.x * 1024 + tid * 4;
    int v0 = 0, v1 = 0, v2 = 0, v3 = 0;
    if (base + 0 < n) v0 = in[base + 0];
    if (base + 1 < n) v1 = in[base + 1];
    if (base + 2 < n) v2 = in[base + 2];
    if (base + 3 < n) v3 = in[base + 3];
    int s = v0 + v1 + v2 + v3;
    lds[tid] = s;
    __syncthreads();
    for (int off = 1; off < 256; off <<= 1) {
        int val = (tid >= off) ? lds[tid - off] : 0;
        __syncthreads();
        lds[tid] += val;
        __syncthreads();
    }
    int excl = lds[tid] - s;
    if (tid == 255) bsum[blockIdx.x] = lds[255];
    if (base + 0 < n) out[base + 0] = excl;
    if (base + 1 < n) out[base + 1] = excl + v0;
    if (base + 2 < n) out[base + 2] = excl + v0 + v1;
    if (base + 3 < n) out[base + 3] = excl + v0 + v1 + v2;
}

// wave-parallel exclusive scan of bsum (chunked shuffle scan with carry)
__global__ void scan_top(int* __restrict__ bsum, int nb) {
    int lane = threadIdx.x;  // 64 threads
    int carry = 0;
    for (int base = 0; base < nb; base += 64) {
        int i = base + lane;
        int orig = (i < nb) ? bsum[i] : 0;
        int v = orig;
#pragma unroll
        for (int off = 1; off < 64; off <<= 1) {
            int t = __shfl_up(v, off, 64);
            if (lane >= off) v += t;
        }
        if (i < nb) bsum[i] = carry + v - orig;   // exclusive
        carry += __shfl(v, 63, 64);
    }
}

__global__ void scan_add(int* __restrict__ data, const int* __restrict__ bsum, int n) {
    int i = blockIdx.x * 256 + threadIdx.x;
    if (i < n) data[i] += bsum[i >> 10];
}

// single global read: pack each edge into LDS at its sorted slot, then
// slot-major burst writes to tre.
__global__ __launch_bounds__(1024)
void scatter_bkt(const int* __restrict__ ei, const float* __restrict__ ew,
                 const int* __restrict__ cnt2, const int* __restrict__ scanned,
                 int2* __restrict__ tre) {
    __shared__ int2 pay[EPB];      // 50 KB
    __shared__ int scur[NBKT];
    __shared__ int hexc[NBKT];
    __shared__ int gbase[NBKT];
    int tid = threadIdx.x, blk = blockIdx.x;
    int myh = 0;
    if (tid < NBKT) {
        myh = cnt2[tid * NBLK + blk];
        gbase[tid] = scanned[tid * NBLK + blk];
        scur[tid] = myh;
    }
    __syncthreads();
    for (int off = 1; off < NBKT; off <<= 1) {
        int v = (tid < NBKT && tid >= off) ? scur[tid - off] : 0;
        __syncthreads();
        if (tid < NBKT) scur[tid] += v;
        __syncthreads();
    }
    if (tid < NBKT) { int ex = scur[tid] - myh; hexc[tid] = ex; scur[tid] = ex; }
    __syncthreads();
    int base = blk * EPB;
    for (int i = tid; i < EPB; i += 1024) {
        int e = base + i;
        int c = ei[NE + e];
        int r = ei[e];
        unsigned int wb = __float_as_uint(ew[e]);
        int b = c >> 7;
        int j = atomicAdd(&scur[b], 1);
        pay[j] = make_int2(r | ((c & 127) << 17) | ((b & 0xFF) << 24),
                           (int)((wb & ~3u) | ((unsigned)b >> 8)));
    }
    __syncthreads();
    for (int j = tid; j < EPB; j += 1024) {
        int2 q = pay[j];
        int b = (int)((((unsigned)q.y & 3u) << 8) | (((unsigned)q.x >> 24) & 0xFFu));
        int pos = gbase[b] + (j - hexc[b]);
        tre[pos] = make_int2(q.x & 0x00FFFFFF, q.y & ~3);
    }
}

// per bucket: stream tre, LDS-accumulate weighted in-degree, write dinv
__global__ __launch_bounds__(512)
void deg_k(const int2* __restrict__ tre, const int* __restrict__ scanned,
           float* __restrict__ dinv) {
    __shared__ float dw[128];
    int b = blockIdx.x, tid = threadIdx.x;
    int base = scanned[b * NBLK];
    int end = (b == NBKT - 1) ? NE : scanned[(b + 1) * NBLK];
    if (tid < 128) dw[tid] = 0.f;
    __syncthreads();
    for (int i = base + tid; i < end; i += 512) {
        int2 q = tre[i];
        atomicAdd(&dw[(q.x >> 17) & 127], __int_as_float(q.y));
    }
    __syncthreads();
    if (tid < 128) {
        int node = b * 128 + tid;
        if (node < NN) dinv[node] = rsqrtf(1.0f + dw[tid]);
    }
}

// per bucket: stage in LDS, 128-bin count+scan, emit node-sorted 4B packed
// edges: src(17b) | sign-free bf16 of (ew*dinv[src]) (15b). Also rowptr.
__global__ __launch_bounds__(512)
void sort_k(const int2* __restrict__ tre, const int* __restrict__ scanned,
            const float* __restrict__ dinv,
            unsigned int* __restrict__ srn4, int* __restrict__ rowptr) {
    __shared__ int2 ed[BCAP];      // 40 KB
    __shared__ int h[128];
    __shared__ int sc[128];
    __shared__ int cur[128];
    int b = blockIdx.x, tid = threadIdx.x;
    int base = scanned[b * NBLK];
    int end = (b == NBKT - 1) ? NE : scanned[(b + 1) * NBLK];
    int n = end - base;
    bool staged = (n <= BCAP);
    if (tid < 128) h[tid] = 0;
    if (staged)
        for (int i = tid; i < n; i += 512) ed[i] = tre[base + i];
    __syncthreads();
    for (int i = tid; i < n; i += 512) {
        int2 q = staged ? ed[i] : tre[base + i];
        atomicAdd(&h[(q.x >> 17) & 127], 1);
    }
    __syncthreads();
    if (tid < 128) sc[tid] = h[tid];
    __syncthreads();
    for (int off = 1; off < 128; off <<= 1) {
        int v = (tid < 128 && tid >= off) ? sc[tid - off] : 0;
        __syncthreads();
        if (tid < 128) sc[tid] += v;
        __syncthreads();
    }
    if (tid < 128) {
        int node = b * 128 + tid;
        if (node < NN) rowptr[node] = base + sc[tid];     // end offset
        cur[tid] = base + sc[tid] - h[tid];               // start cursor
    }
    __syncthreads();
    for (int i = tid; i < n; i += 512) {
        int2 q = staged ? ed[i] : tre[base + i];
        int key = (q.x >> 17) & 127;
        int pos = atomicAdd(&cur[key], 1);
        unsigned int src = (unsigned)(q.x & SRCMASK);
        float w = __int_as_float(q.y) * dinv[src];
        unsigned int wb = __float_as_uint(w);
        wb += 0x7FFFu + ((wb >> 16) & 1u);               // RNE to bf16
        srn4[pos] = src | (((wb >> 16) & 0x7FFFu) << 17);
    }
}

// LDS-tiled linear: 64-row x tile (padded, coalesced staging, relu folded),
// W pre-swizzled to wp[j*8+kg] = W[j][4kg..4kg+3]; thread = 2 rows x 4
// CONTIGUOUS cols; output packed to fp8 e4m3 (one 4B word per row per thread).
template <int IN_DIM, bool RELU_IN>
__global__ __launch_bounds__(256)
void linear_k(const float* __restrict__ in, const float* __restrict__ W,
              unsigned int* __restrict__ tmp8) {
    constexpr int J4 = IN_DIM / 4;       // 32 or 8
    constexpr int XSS = J4 + 1;          // padded row stride (float4)
    __shared__ float4 xs[64 * XSS];
    __shared__ float4 wp[IN_DIM * 8];
    int tid = threadIdx.x;
    for (int idx = tid; idx < IN_DIM * 8; idx += 256) {
        int j = idx >> 3, kg = idx & 7;
        const float* wr = W + j * 32 + kg * 4;
        wp[idx] = make_float4(wr[0], wr[1], wr[2], wr[3]);
    }
    int rbase = blockIdx.x * 64;
    const float4* in4 = (const float4*)in;
    for (int idx = tid; idx < 64 * J4; idx += 256) {
        int row = idx / J4, j4 = idx % J4;
        int grow = rbase + row;
        float4 v = (grow < NN) ? in4[(size_t)grow * J4 + j4]
                               : make_float4(0.f, 0.f, 0.f, 0.f);
        if (RELU_IN) {
            v.x = fmaxf(v.x, 0.f); v.y = fmaxf(v.y, 0.f);
            v.z = fmaxf(v.z, 0.f); v.w = fmaxf(v.w, 0.f);
        }
        xs[row * XSS + j4] = v;
    }
    __syncthreads();
    int kg = tid & 7;          // cols 4kg..4kg+3
    int rp = tid >> 3;         // rows 2rp, 2rp+1
    int r0 = rbase + 2 * rp;
    if (r0 >= NN) return;
    const float4* x0 = &xs[(2 * rp) * XSS];
    const float4* x1 = &xs[(2 * rp + 1) * XSS];
    float a00 = 0, a01 = 0, a02 = 0, a03 = 0;
    float a10 = 0, a11 = 0, a12 = 0, a13 = 0;
#pragma unroll
    for (int j4 = 0; j4 < J4; ++j4) {
        float4 v0 = x0[j4], v1 = x1[j4];
        const float4* wj = &wp[j4 * 4 * 8 + kg];
        float4 w0 = wj[0], w1 = wj[8], w2 = wj[16], w3 = wj[24];
#define LSTEP(VX0, VX1, W4) \
        a00 = fmaf(VX0, W4.x, a00); a01 = fmaf(VX0, W4.y, a01); \
        a02 = fmaf(VX0, W4.z, a02); a03 = fmaf(VX0, W4.w, a03); \
        a10 = fmaf(VX1, W4.x, a10); a11 = fmaf(VX1, W4.y, a11); \
        a12 = fmaf(VX1, W4.z, a12); a13 = fmaf(VX1, W4.w, a13);
        LSTEP(v0.x, v1.x, w0)
        LSTEP(v0.y, v1.y, w1)
        LSTEP(v0.z, v1.z, w2)
        LSTEP(v0.w, v1.w, w3)
#undef LSTEP
    }
    int q0 = __builtin_amdgcn_cvt_pk_fp8_f32(a00, a01, 0, false);
    q0 = __builtin_amdgcn_cvt_pk_fp8_f32(a02, a03, q0, true);
    int q1 = __builtin_amdgcn_cvt_pk_fp8_f32(a10, a11, 0, false);
    q1 = __builtin_amdgcn_cvt_pk_fp8_f32(a12, a13, q1, true);
    tmp8[r0 * 8 + kg] = (unsigned int)q0;
    tmp8[(r0 + 1) * 8 + kg] = (unsigned int)q1;
}

// one wave per dest node: 64 lanes = 8 feat-quads x 8 edge slots.
// Per edge, lane gathers ONE 4B fp8-quad (tmp8 is 3.2 MB -> L2-resident);
// native v_cvt_pk_f32_fp8 decode. h = bias + dinv^2*self + dinv*sum(w*msg).
__global__ void aggregate(const unsigned int* __restrict__ srn4,
                          const int* __restrict__ rowptr,
                          const float* __restrict__ dinv,
                          const float* __restrict__ bias,
                          const unsigned int* __restrict__ tmp8,
                          float* __restrict__ h) {
    int wid = (blockIdx.x * 256 + threadIdx.x) >> 6;
    if (wid >= NN) return;
    int lane = threadIdx.x & 63;
    int g = lane >> 3;      // edge slot 0..7
    int q = lane & 7;       // feat quad (feats 4q..4q+3)
    int end = rowptr[wid];
    int start = (wid == 0) ? 0 : rowptr[wid - 1];
    float a0 = 0, a1 = 0, a2 = 0, a3 = 0;
    float b0 = 0, b1 = 0, b2 = 0, b3 = 0;
    int e = start + g;
    for (; e + 8 < end; e += 16) {
        unsigned int p0 = srn4[e];
        unsigned int p1 = srn4[e + 8];
        unsigned int u0 = tmp8[(size_t)(p0 & SRCMASK) * 8 + q];
        unsigned int u1 = tmp8[(size_t)(p1 & SRCMASK) * 8 + q];
        float w0 = __uint_as_float((p0 >> 1) & 0x7FFF0000u);
        float w1 = __uint_as_float((p1 >> 1) & 0x7FFF0000u);
        floatx2 lo0 = __builtin_amdgcn_cvt_pk_f32_fp8(u0, false);
        floatx2 hi0 = __builtin_amdgcn_cvt_pk_f32_fp8(u0, true);
        floatx2 lo1 = __builtin_amdgcn_cvt_pk_f32_fp8(u1, false);
        floatx2 hi1 = __builtin_amdgcn_cvt_pk_f32_fp8(u1, true);
        a0 = fmaf(w0, lo0.x, a0); a1 = fmaf(w0, lo0.y, a1);
        a2 = fmaf(w0, hi0.x, a2); a3 = fmaf(w0, hi0.y, a3);
        b0 = fmaf(w1, lo1.x, b0); b1 = fmaf(w1, lo1.y, b1);
        b2 = fmaf(w1, hi1.x, b2); b3 = fmaf(w1, hi1.y, b3);
    }
    if (e < end) {
        unsigned int p = srn4[e];
        unsigned int u = tmp8[(size_t)(p & SRCMASK) * 8 + q];
        float w = __uint_as_float((p >> 1) & 0x7FFF0000u);
        floatx2 lo = __builtin_amdgcn_cvt_pk_f32_fp8(u, false);
        floatx2 hi = __builtin_amdgcn_cvt_pk_f32_fp8(u, true);
        a0 = fmaf(w, lo.x, a0); a1 = fmaf(w, lo.y, a1);
        a2 = fmaf(w, hi.x, a2); a3 = fmaf(w, hi.y, a3);
    }
    a0 += b0; a1 += b1; a2 += b2; a3 += b3;
    a0 += __shfl_xor(a0, 8, 64); a1 += __shfl_xor(a1, 8, 64);
    a2 += __shfl_xor(a2, 8, 64); a3 += __shfl_xor(a3, 8, 64);
    a0 += __shfl_xor(a0, 16, 64); a1 += __shfl_xor(a1, 16, 64);
    a2 += __shfl_xor(a2, 16, 64); a3 += __shfl_xor(a3, 16, 64);
    a0 += __shfl_xor(a0, 32, 64); a1 += __shfl_xor(a1, 32, 64);
    a2 += __shfl_xor(a2, 32, 64); a3 += __shfl_xor(a3, 32, 64);
    if (g == 0) {
        float d = dinv[wid];
        float d2 = d * d;
        unsigned int sv = tmp8[(size_t)wid * 8 + q];
        floatx2 slo = __builtin_amdgcn_cvt_pk_f32_fp8(sv, false);
        floatx2 shi = __builtin_amdgcn_cvt_pk_f32_fp8(sv, true);
        float4 bq = ((const float4*)bias)[q];
        float4 o;
        o.x = bq.x + d2 * slo.x + d * a0;
        o.y = bq.y + d2 * slo.y + d * a1;
        o.z = bq.z + d2 * shi.x + d * a2;
        o.w = bq.w + d2 * shi.y + d * a3;
        ((float4*)(h + (size_t)wid * HID))[q] = o;
    }
}

// sorted-batch run-length pooling
__global__ void pool_k(const float* __restrict__ h, const int* __restrict__ batch,
                       float* __restrict__ sums, float* __restrict__ counts) {
    int t = blockIdx.x * 256 + threadIdx.x;
    int chunk = t >> 5, k = t & 31;
    int n0 = chunk * 32;
    if (n0 >= NN) return;
    int n1 = min(n0 + 32, NN);
    int g = batch[n0];
    float acc = 0.f, cacc = 0.f;
    for (int i = n0; i < n1; ++i) {
        int gi = batch[i];
        if (gi != g) {
            atomicAdd(&sums[g * HID + k], acc);
            if (k == 0) atomicAdd(&counts[g], cacc);
            g = gi; acc = 0.f; cacc = 0.f;
        }
        acc += h[(size_t)i * HID + k];
        cacc += 1.f;
    }
    atomicAdd(&sums[g * HID + k], acc);
    if (k == 0) atomicAdd(&counts[g], cacc);
}

// whole MLP in one block
__global__ void mlp_k(const float* __restrict__ sums, const float* __restrict__ counts,
                      const float* __restrict__ Wm0, const float* __restrict__ bm0,
                      const float* __restrict__ Wm1, const float* __restrict__ bm1,
                      const float* __restrict__ Wout, const float* __restrict__ bout,
                      float* __restrict__ out) {
    __shared__ float g0[NG * HID];
    __shared__ float g1[NG * MH];
    __shared__ float g2[NG * MH];
    int tid = threadIdx.x;
    for (int idx = tid; idx < NG * HID; idx += 256) {
        int g = idx / HID;
        g0[idx] = sums[idx] / fmaxf(counts[g], 1.0f);
    }
    __syncthreads();
    for (int idx = tid; idx < NG * MH; idx += 256) {
        int g = idx / MH, k = idx % MH;
        float acc = bm0[k];
        for (int j = 0; j < HID; ++j) acc = fmaf(g0[g * HID + j], Wm0[j * MH + k], acc);
        g1[idx] = fmaxf(acc, 0.f);
    }
    __syncthreads();
    for (int idx = tid; idx < NG * MH; idx += 256) {
        int g = idx / MH, k = idx % MH;
        float acc = bm1[k];
        for (int j = 0; j < MH; ++j) acc = fmaf(g1[g * MH + j], Wm1[j * MH + k], acc);
        g2[idx] = fmaxf(acc, 0.f);
    }
    __syncthreads();
    for (int idx = tid; idx < NG * NC; idx += 256) {
        int g = idx / NC, k = idx % NC;
        float acc = bout[k];
        for (int j = 0; j < MH; ++j) acc = fmaf(g2[g * MH + j], Wout[j * NC + k], acc);
        out[idx] = acc;
    }
}

extern "C" void kernel_launch(void* const* d_in, const int* in_sizes, int n_in,
                              void* d_out, int out_size, void* d_ws, size_t ws_size,
                              hipStream_t stream) {
    const float* x    = (const float*)d_in[0];
    const int*   ei   = (const int*)d_in[1];
    const float* ew   = (const float*)d_in[2];
    const int*   batch= (const int*)d_in[3];
    const float* W1   = (const float*)d_in[4];
    const float* b1   = (const float*)d_in[5];
    const float* W2   = (const float*)d_in[6];
    const float* b2   = (const float*)d_in[7];
    const float* W3   = (const float*)d_in[8];
    const float* b3   = (const float*)d_in[9];
    const float* Wm0  = (const float*)d_in[10];
    const float* bm0  = (const float*)d_in[11];
    const float* Wm1  = (const float*)d_in[12];
    const float* bm1  = (const float*)d_in[13];
    const float* Wout = (const float*)d_in[14];
    const float* bout = (const float*)d_in[15];
    float* out = (float*)d_out;

    // workspace: srn4 | S (tre+cnt2+scanned <-> tmp8+hA+hB) | small bufs
    char* p = (char*)d_ws;
    unsigned int* srn4 = (unsigned int*)p; p += sizeof(unsigned int) * (size_t)NE; // 12.8 MB
    char*  S   = p;                      p += 12 * (size_t)NE;                // 38.4 MB shared
    int2*  tre = (int2*)S;                                                    // 25.6 MB
    int*   cnt2    = (int*)(S + sizeof(int2) * (size_t)NE);                   // 1.6 MB (dies pre-layer1)
    int*   scanned = cnt2 + SCANL;                                            // 1.6 MB
    unsigned int* tmp8 = (unsigned int*)S;                                    // 3.2 MB
    float* hA  = (float*)(S + (size_t)NN * HID);                              // 12.8 MB
    float* hB  = hA + (size_t)NN * HID;                                       // 12.8 MB
    int*   bsum    = (int*)p;            p += sizeof(int) * 512;
    float* dinv    = (float*)p;          p += sizeof(float) * NN;
    int*   rowptr  = (int*)p;            p += sizeof(int) * NN;
    float* sums    = (float*)p;          p += sizeof(float) * NG * HID;
    float* counts  = (float*)p;

    dim3 blk(256);
    const int NB_SCAN = (SCANL + 1023) / 1024;  // 391
    const int NB_LIN = (NN + 63) / 64;          // 1563

    init_misc<<<9, blk, 0, stream>>>(sums);
    hist_bkt<<<NBLK, 1024, 0, stream>>>(ei, cnt2);
    scan_block<<<NB_SCAN, blk, 0, stream>>>(cnt2, scanned, bsum, SCANL);
    scan_top<<<1, 64, 0, stream>>>(bsum, NB_SCAN);
    scan_add<<<(SCANL + 255) / 256, blk, 0, stream>>>(scanned, bsum, SCANL);
    scatter_bkt<<<NBLK, 1024, 0, stream>>>(ei, ew, cnt2, scanned, tre);
    deg_k<<<NBKT, 512, 0, stream>>>(tre, scanned, dinv);
    sort_k<<<NBKT, 512, 0, stream>>>(tre, scanned, dinv, srn4, rowptr);

    // layer 1
    linear_k<FIN, false><<<NB_LIN, blk, 0, stream>>>(x, W1, tmp8);
    aggregate<<<25000, blk, 0, stream>>>(srn4, rowptr, dinv, b1, tmp8, hA);
    // layer 2
    linear_k<HID, true><<<NB_LIN, blk, 0, stream>>>(hA, W2, tmp8);
    aggregate<<<25000, blk, 0, stream>>>(srn4, rowptr, dinv, b2, tmp8, hB);
    // layer 3
    linear_k<HID, true><<<NB_LIN, blk, 0, stream>>>(hB, W3, tmp8);
    aggregate<<<25000, blk, 0, stream>>>(srn4, rowptr, dinv, b3, tmp8, hA);

    pool_k<<<391, blk, 0, stream>>>(hA, batch, sums, counts);
    mlp_k<<<1, blk, 0, stream>>>(sums, counts, Wm0, bm0, Wm1, bm1, Wout, bout, out);
}

// Round 11
// 422.303 us; speedup vs baseline: 11.9026x; 1.0916x over previous
//
#include <hip/hip_runtime.h>

#define NN 100000
#define NE 3200000
#define FIN 128
#define HID 32
#define MH  64
#define NC  10
#define NG  64
#define NBKT 782           // ceil(NN/128) buckets of 128 dest nodes
#define NBLK 512           // edge-pass blocks
#define EPB  (NE / NBLK)   // 6250 edges per block
#define SCANL (NBKT * NBLK)
#define SRCMASK 0x1FFFF    // src < 100000 < 2^17
#define BCAP 5120          // bucket LDS capacity (mean 4092, sd ~64)

typedef float floatx2 __attribute__((ext_vector_type(2)));

__global__ void init_misc(float* __restrict__ sc) {
    int i = blockIdx.x * 256 + threadIdx.x;
    if (i < NG * HID + NG) sc[i] = 0.0f;
}

// per-block LDS histogram over 782 dest-buckets; no global atomics
__global__ __launch_bounds__(1024)
void hist_bkt(const int* __restrict__ ei, int* __restrict__ cnt2) {
    __shared__ int h[NBKT];
    int tid = threadIdx.x, blk = blockIdx.x;
    for (int b = tid; b < NBKT; b += 1024) h[b] = 0;
    __syncthreads();
    int base = blk * EPB;
    for (int i = tid; i < EPB; i += 1024)
        atomicAdd(&h[ei[NE + base + i] >> 7], 1);
    __syncthreads();
    for (int b = tid; b < NBKT; b += 1024) cnt2[b * NBLK + blk] = h[b];
}

// ---- generic exclusive scan (1024 elems/block) ----
__global__ void scan_block(const int* __restrict__ in, int* __restrict__ out,
                           int* __restrict__ bsum, int n) {
    __shared__ int lds[256];
    int tid = threadIdx.x;
    int base = blockIdx.x * 1024 + tid * 4;
    int v0 = 0, v1 = 0, v2 = 0, v3 = 0;
    if (base + 0 < n) v0 = in[base + 0];
    if (base + 1 < n) v1 = in[base + 1];
    if (base + 2 < n) v2 = in[base + 2];
    if (base + 3 < n) v3 = in[base + 3];
    int s = v0 + v1 + v2 + v3;
    lds[tid] = s;
    __syncthreads();
    for (int off = 1; off < 256; off <<= 1) {
        int val = (tid >= off) ? lds[tid - off] : 0;
        __syncthreads();
        lds[tid] += val;
        __syncthreads();
    }
    int excl = lds[tid] - s;
    if (tid == 255) bsum[blockIdx.x] = lds[255];
    if (base + 0 < n) out[base + 0] = excl;
    if (base + 1 < n) out[base + 1] = excl + v0;
    if (base + 2 < n) out[base + 2] = excl + v0 + v1;
    if (base + 3 < n) out[base + 3] = excl + v0 + v1 + v2;
}

// wave-parallel exclusive scan of bsum (chunked shuffle scan with carry)
__global__ void scan_top(int* __restrict__ bsum, int nb) {
    int lane = threadIdx.x;  // 64 threads
    int carry = 0;
    for (int base = 0; base < nb; base += 64) {
        int i = base + lane;
        int orig = (i < nb) ? bsum[i] : 0;
        int v = orig;
#pragma unroll
        for (int off = 1; off < 64; off <<= 1) {
            int t = __shfl_up(v, off, 64);
            if (lane >= off) v += t;
        }
        if (i < nb) bsum[i] = carry + v - orig;   // exclusive
        carry += __shfl(v, 63, 64);
    }
}

__global__ void scan_add(int* __restrict__ data, const int* __restrict__ bsum, int n) {
    int i = blockIdx.x * 256 + threadIdx.x;
    if (i < n) data[i] += bsum[i >> 10];
}

// single global read: pack each edge into LDS at its sorted slot, then
// slot-major burst writes to tre.
__global__ __launch_bounds__(1024)
void scatter_bkt(const int* __restrict__ ei, const float* __restrict__ ew,
                 const int* __restrict__ cnt2, const int* __restrict__ scanned,
                 int2* __restrict__ tre) {
    __shared__ int2 pay[EPB];      // 50 KB
    __shared__ int scur[NBKT];
    __shared__ int hexc[NBKT];
    __shared__ int gbase[NBKT];
    int tid = threadIdx.x, blk = blockIdx.x;
    int myh = 0;
    if (tid < NBKT) {
        myh = cnt2[tid * NBLK + blk];
        gbase[tid] = scanned[tid * NBLK + blk];
        scur[tid] = myh;
    }
    __syncthreads();
    for (int off = 1; off < NBKT; off <<= 1) {
        int v = (tid < NBKT && tid >= off) ? scur[tid - off] : 0;
        __syncthreads();
        if (tid < NBKT) scur[tid] += v;
        __syncthreads();
    }
    if (tid < NBKT) { int ex = scur[tid] - myh; hexc[tid] = ex; scur[tid] = ex; }
    __syncthreads();
    int base = blk * EPB;
    for (int i = tid; i < EPB; i += 1024) {
        int e = base + i;
        int c = ei[NE + e];
        int r = ei[e];
        unsigned int wb = __float_as_uint(ew[e]);
        int b = c >> 7;
        int j = atomicAdd(&scur[b], 1);
        pay[j] = make_int2(r | ((c & 127) << 17) | ((b & 0xFF) << 24),
                           (int)((wb & ~3u) | ((unsigned)b >> 8)));
    }
    __syncthreads();
    for (int j = tid; j < EPB; j += 1024) {
        int2 q = pay[j];
        int b = (int)((((unsigned)q.y & 3u) << 8) | (((unsigned)q.x >> 24) & 0xFFu));
        int pos = gbase[b] + (j - hexc[b]);
        tre[pos] = make_int2(q.x & 0x00FFFFFF, q.y & ~3);
    }
}

// per bucket: stream tre, LDS-accumulate weighted in-degree, write dinv
__global__ __launch_bounds__(512)
void deg_k(const int2* __restrict__ tre, const int* __restrict__ scanned,
           float* __restrict__ dinv) {
    __shared__ float dw[128];
    int b = blockIdx.x, tid = threadIdx.x;
    int base = scanned[b * NBLK];
    int end = (b == NBKT - 1) ? NE : scanned[(b + 1) * NBLK];
    if (tid < 128) dw[tid] = 0.f;
    __syncthreads();
    for (int i = base + tid; i < end; i += 512) {
        int2 q = tre[i];
        atomicAdd(&dw[(q.x >> 17) & 127], __int_as_float(q.y));
    }
    __syncthreads();
    if (tid < 128) {
        int node = b * 128 + tid;
        if (node < NN) dinv[node] = rsqrtf(1.0f + dw[tid]);
    }
}

// per bucket: stage in LDS, 128-bin count+scan, emit node-sorted 4B packed
// edges: src(17b) | sign-free bf16 of (ew*dinv[src]) (15b). Also rowptr.
__global__ __launch_bounds__(512)
void sort_k(const int2* __restrict__ tre, const int* __restrict__ scanned,
            const float* __restrict__ dinv,
            unsigned int* __restrict__ srn4, int* __restrict__ rowptr) {
    __shared__ int2 ed[BCAP];      // 40 KB
    __shared__ int h[128];
    __shared__ int sc[128];
    __shared__ int cur[128];
    int b = blockIdx.x, tid = threadIdx.x;
    int base = scanned[b * NBLK];
    int end = (b == NBKT - 1) ? NE : scanned[(b + 1) * NBLK];
    int n = end - base;
    bool staged = (n <= BCAP);
    if (tid < 128) h[tid] = 0;
    if (staged)
        for (int i = tid; i < n; i += 512) ed[i] = tre[base + i];
    __syncthreads();
    for (int i = tid; i < n; i += 512) {
        int2 q = staged ? ed[i] : tre[base + i];
        atomicAdd(&h[(q.x >> 17) & 127], 1);
    }
    __syncthreads();
    if (tid < 128) sc[tid] = h[tid];
    __syncthreads();
    for (int off = 1; off < 128; off <<= 1) {
        int v = (tid < 128 && tid >= off) ? sc[tid - off] : 0;
        __syncthreads();
        if (tid < 128) sc[tid] += v;
        __syncthreads();
    }
    if (tid < 128) {
        int node = b * 128 + tid;
        if (node < NN) rowptr[node] = base + sc[tid];     // end offset
        cur[tid] = base + sc[tid] - h[tid];               // start cursor
    }
    __syncthreads();
    for (int i = tid; i < n; i += 512) {
        int2 q = staged ? ed[i] : tre[base + i];
        int key = (q.x >> 17) & 127;
        int pos = atomicAdd(&cur[key], 1);
        unsigned int src = (unsigned)(q.x & SRCMASK);
        float w = __int_as_float(q.y) * dinv[src];
        unsigned int wb = __float_as_uint(w);
        wb += 0x7FFFu + ((wb >> 16) & 1u);               // RNE to bf16
        srn4[pos] = src | (((wb >> 16) & 0x7FFFu) << 17);
    }
}

// LDS-tiled linear: 64-row x tile (padded, coalesced staging, relu folded),
// W pre-swizzled to wp[j*8+kg] = W[j][4kg..4kg+3]; thread = 2 rows x 4
// CONTIGUOUS cols; output packed to fp8 e4m3 (one 4B word per row per thread).
template <int IN_DIM, bool RELU_IN>
__global__ __launch_bounds__(256)
void linear_k(const float* __restrict__ in, const float* __restrict__ W,
              unsigned int* __restrict__ tmp8) {
    constexpr int J4 = IN_DIM / 4;       // 32 or 8
    constexpr int XSS = J4 + 1;          // padded row stride (float4)
    __shared__ float4 xs[64 * XSS];
    __shared__ float4 wp[IN_DIM * 8];
    int tid = threadIdx.x;
    for (int idx = tid; idx < IN_DIM * 8; idx += 256) {
        int j = idx >> 3, kg = idx & 7;
        const float* wr = W + j * 32 + kg * 4;
        wp[idx] = make_float4(wr[0], wr[1], wr[2], wr[3]);
    }
    int rbase = blockIdx.x * 64;
    const float4* in4 = (const float4*)in;
    for (int idx = tid; idx < 64 * J4; idx += 256) {
        int row = idx / J4, j4 = idx % J4;
        int grow = rbase + row;
        float4 v = (grow < NN) ? in4[(size_t)grow * J4 + j4]
                               : make_float4(0.f, 0.f, 0.f, 0.f);
        if (RELU_IN) {
            v.x = fmaxf(v.x, 0.f); v.y = fmaxf(v.y, 0.f);
            v.z = fmaxf(v.z, 0.f); v.w = fmaxf(v.w, 0.f);
        }
        xs[row * XSS + j4] = v;
    }
    __syncthreads();
    int kg = tid & 7;          // cols 4kg..4kg+3
    int rp = tid >> 3;         // rows 2rp, 2rp+1
    int r0 = rbase + 2 * rp;
    if (r0 >= NN) return;
    const float4* x0 = &xs[(2 * rp) * XSS];
    const float4* x1 = &xs[(2 * rp + 1) * XSS];
    float a00 = 0, a01 = 0, a02 = 0, a03 = 0;
    float a10 = 0, a11 = 0, a12 = 0, a13 = 0;
#pragma unroll
    for (int j4 = 0; j4 < J4; ++j4) {
        float4 v0 = x0[j4], v1 = x1[j4];
        const float4* wj = &wp[j4 * 4 * 8 + kg];
        float4 w0 = wj[0], w1 = wj[8], w2 = wj[16], w3 = wj[24];
#define LSTEP(VX0, VX1, W4) \
        a00 = fmaf(VX0, W4.x, a00); a01 = fmaf(VX0, W4.y, a01); \
        a02 = fmaf(VX0, W4.z, a02); a03 = fmaf(VX0, W4.w, a03); \
        a10 = fmaf(VX1, W4.x, a10); a11 = fmaf(VX1, W4.y, a11); \
        a12 = fmaf(VX1, W4.z, a12); a13 = fmaf(VX1, W4.w, a13);
        LSTEP(v0.x, v1.x, w0)
        LSTEP(v0.y, v1.y, w1)
        LSTEP(v0.z, v1.z, w2)
        LSTEP(v0.w, v1.w, w3)
#undef LSTEP
    }
    int q0 = __builtin_amdgcn_cvt_pk_fp8_f32(a00, a01, 0, false);
    q0 = __builtin_amdgcn_cvt_pk_fp8_f32(a02, a03, q0, true);
    int q1 = __builtin_amdgcn_cvt_pk_fp8_f32(a10, a11, 0, false);
    q1 = __builtin_amdgcn_cvt_pk_fp8_f32(a12, a13, q1, true);
    tmp8[r0 * 8 + kg] = (unsigned int)q0;
    tmp8[(r0 + 1) * 8 + kg] = (unsigned int)q1;
}

// one wave per dest node: 64 lanes = 8 feat-quads x 8 edge slots.
// Per edge, lane gathers ONE 4B fp8-quad (tmp8 is 3.2 MB -> L2-resident);
// native v_cvt_pk_f32_fp8 decode. h = bias + dinv^2*self + dinv*sum(w*msg).
__global__ void aggregate(const unsigned int* __restrict__ srn4,
                          const int* __restrict__ rowptr,
                          const float* __restrict__ dinv,
                          const float* __restrict__ bias,
                          const unsigned int* __restrict__ tmp8,
                          float* __restrict__ h) {
    int wid = (blockIdx.x * 256 + threadIdx.x) >> 6;
    if (wid >= NN) return;
    int lane = threadIdx.x & 63;
    int g = lane >> 3;      // edge slot 0..7
    int q = lane & 7;       // feat quad (feats 4q..4q+3)
    int end = rowptr[wid];
    int start = (wid == 0) ? 0 : rowptr[wid - 1];
    float a0 = 0, a1 = 0, a2 = 0, a3 = 0;
    float b0 = 0, b1 = 0, b2 = 0, b3 = 0;
    int e = start + g;
    for (; e + 8 < end; e += 16) {
        unsigned int p0 = srn4[e];
        unsigned int p1 = srn4[e + 8];
        unsigned int u0 = tmp8[(size_t)(p0 & SRCMASK) * 8 + q];
        unsigned int u1 = tmp8[(size_t)(p1 & SRCMASK) * 8 + q];
        float w0 = __uint_as_float((p0 >> 1) & 0x7FFF0000u);
        float w1 = __uint_as_float((p1 >> 1) & 0x7FFF0000u);
        floatx2 lo0 = __builtin_amdgcn_cvt_pk_f32_fp8(u0, false);
        floatx2 hi0 = __builtin_amdgcn_cvt_pk_f32_fp8(u0, true);
        floatx2 lo1 = __builtin_amdgcn_cvt_pk_f32_fp8(u1, false);
        floatx2 hi1 = __builtin_amdgcn_cvt_pk_f32_fp8(u1, true);
        a0 = fmaf(w0, lo0.x, a0); a1 = fmaf(w0, lo0.y, a1);
        a2 = fmaf(w0, hi0.x, a2); a3 = fmaf(w0, hi0.y, a3);
        b0 = fmaf(w1, lo1.x, b0); b1 = fmaf(w1, lo1.y, b1);
        b2 = fmaf(w1, hi1.x, b2); b3 = fmaf(w1, hi1.y, b3);
    }
    if (e < end) {
        unsigned int p = srn4[e];
        unsigned int u = tmp8[(size_t)(p & SRCMASK) * 8 + q];
        float w = __uint_as_float((p >> 1) & 0x7FFF0000u);
        floatx2 lo = __builtin_amdgcn_cvt_pk_f32_fp8(u, false);
        floatx2 hi = __builtin_amdgcn_cvt_pk_f32_fp8(u, true);
        a0 = fmaf(w, lo.x, a0); a1 = fmaf(w, lo.y, a1);
        a2 = fmaf(w, hi.x, a2); a3 = fmaf(w, hi.y, a3);
    }
    a0 += b0; a1 += b1; a2 += b2; a3 += b3;
    a0 += __shfl_xor(a0, 8, 64); a1 += __shfl_xor(a1, 8, 64);
    a2 += __shfl_xor(a2, 8, 64); a3 += __shfl_xor(a3, 8, 64);
    a0 += __shfl_xor(a0, 16, 64); a1 += __shfl_xor(a1, 16, 64);
    a2 += __shfl_xor(a2, 16, 64); a3 += __shfl_xor(a3, 16, 64);
    a0 += __shfl_xor(a0, 32, 64); a1 += __shfl_xor(a1, 32, 64);
    a2 += __shfl_xor(a2, 32, 64); a3 += __shfl_xor(a3, 32, 64);
    if (g == 0) {
        float d = dinv[wid];
        float d2 = d * d;
        unsigned int sv = tmp8[(size_t)wid * 8 + q];
        floatx2 slo = __builtin_amdgcn_cvt_pk_f32_fp8(sv, false);
        floatx2 shi = __builtin_amdgcn_cvt_pk_f32_fp8(sv, true);
        float4 bq = ((const float4*)bias)[q];
        float4 o;
        o.x = bq.x + d2 * slo.x + d * a0;
        o.y = bq.y + d2 * slo.y + d * a1;
        o.z = bq.z + d2 * shi.x + d * a2;
        o.w = bq.w + d2 * shi.y + d * a3;
        ((float4*)(h + (size_t)wid * HID))[q] = o;
    }
}

// sorted-batch run-length pooling
__global__ void pool_k(const float* __restrict__ h, const int* __restrict__ batch,
                       float* __restrict__ sums, float* __restrict__ counts) {
    int t = blockIdx.x * 256 + threadIdx.x;
    int chunk = t >> 5, k = t & 31;
    int n0 = chunk * 32;
    if (n0 >= NN) return;
    int n1 = min(n0 + 32, NN);
    int g = batch[n0];
    float acc = 0.f, cacc = 0.f;
    for (int i = n0; i < n1; ++i) {
        int gi = batch[i];
        if (gi != g) {
            atomicAdd(&sums[g * HID + k], acc);
            if (k == 0) atomicAdd(&counts[g], cacc);
            g = gi; acc = 0.f; cacc = 0.f;
        }
        acc += h[(size_t)i * HID + k];
        cacc += 1.f;
    }
    atomicAdd(&sums[g * HID + k], acc);
    if (k == 0) atomicAdd(&counts[g], cacc);
}

// MLP: one block per graph, one wave; thread k owns output column k.
// Weight reads are coalesced across the wave and L2-hot (64 blocks share 27KB).
__global__ __launch_bounds__(64)
void mlp_k(const float* __restrict__ sums, const float* __restrict__ counts,
           const float* __restrict__ Wm0, const float* __restrict__ bm0,
           const float* __restrict__ Wm1, const float* __restrict__ bm1,
           const float* __restrict__ Wout, const float* __restrict__ bout,
           float* __restrict__ out) {
    __shared__ float g0[HID];
    __shared__ float g1[MH];
    __shared__ float g2[MH];
    int g = blockIdx.x;       // 0..63
    int k = threadIdx.x;      // 0..63
    if (k < HID) g0[k] = sums[g * HID + k] / fmaxf(counts[g], 1.0f);
    __syncthreads();
    float acc = bm0[k];
#pragma unroll
    for (int j = 0; j < HID; ++j) acc = fmaf(g0[j], Wm0[j * MH + k], acc);
    g1[k] = fmaxf(acc, 0.f);
    __syncthreads();
    float acc2 = bm1[k];
#pragma unroll
    for (int j = 0; j < MH; ++j) acc2 = fmaf(g1[j], Wm1[j * MH + k], acc2);
    g2[k] = fmaxf(acc2, 0.f);
    __syncthreads();
    if (k < NC) {
        float acc3 = bout[k];
#pragma unroll
        for (int j = 0; j < MH; ++j) acc3 = fmaf(g2[j], Wout[j * NC + k], acc3);
        out[g * NC + k] = acc3;
    }
}

extern "C" void kernel_launch(void* const* d_in, const int* in_sizes, int n_in,
                              void* d_out, int out_size, void* d_ws, size_t ws_size,
                              hipStream_t stream) {
    const float* x    = (const float*)d_in[0];
    const int*   ei   = (const int*)d_in[1];
    const float* ew   = (const float*)d_in[2];
    const int*   batch= (const int*)d_in[3];
    const float* W1   = (const float*)d_in[4];
    const float* b1   = (const float*)d_in[5];
    const float* W2   = (const float*)d_in[6];
    const float* b2   = (const float*)d_in[7];
    const float* W3   = (const float*)d_in[8];
    const float* b3   = (const float*)d_in[9];
    const float* Wm0  = (const float*)d_in[10];
    const float* bm0  = (const float*)d_in[11];
    const float* Wm1  = (const float*)d_in[12];
    const float* bm1  = (const float*)d_in[13];
    const float* Wout = (const float*)d_in[14];
    const float* bout = (const float*)d_in[15];
    float* out = (float*)d_out;

    // workspace: srn4 | S (tre+cnt2+scanned <-> tmp8+hA+hB) | small bufs
    char* p = (char*)d_ws;
    unsigned int* srn4 = (unsigned int*)p; p += sizeof(unsigned int) * (size_t)NE; // 12.8 MB
    char*  S   = p;                      p += 12 * (size_t)NE;                // 38.4 MB shared
    int2*  tre = (int2*)S;                                                    // 25.6 MB
    int*   cnt2    = (int*)(S + sizeof(int2) * (size_t)NE);                   // 1.6 MB (dies pre-layer1)
    int*   scanned = cnt2 + SCANL;                                            // 1.6 MB
    unsigned int* tmp8 = (unsigned int*)S;                                    // 3.2 MB
    float* hA  = (float*)(S + (size_t)NN * HID);                              // 12.8 MB
    float* hB  = hA + (size_t)NN * HID;                                       // 12.8 MB
    int*   bsum    = (int*)p;            p += sizeof(int) * 512;
    float* dinv    = (float*)p;          p += sizeof(float) * NN;
    int*   rowptr  = (int*)p;            p += sizeof(int) * NN;
    float* sums    = (float*)p;          p += sizeof(float) * NG * HID;
    float* counts  = (float*)p;

    dim3 blk(256);
    const int NB_SCAN = (SCANL + 1023) / 1024;  // 391
    const int NB_LIN = (NN + 63) / 64;          // 1563

    init_misc<<<9, blk, 0, stream>>>(sums);
    hist_bkt<<<NBLK, 1024, 0, stream>>>(ei, cnt2);
    scan_block<<<NB_SCAN, blk, 0, stream>>>(cnt2, scanned, bsum, SCANL);
    scan_top<<<1, 64, 0, stream>>>(bsum, NB_SCAN);
    scan_add<<<(SCANL + 255) / 256, blk, 0, stream>>>(scanned, bsum, SCANL);
    scatter_bkt<<<NBLK, 1024, 0, stream>>>(ei, ew, cnt2, scanned, tre);
    deg_k<<<NBKT, 512, 0, stream>>>(tre, scanned, dinv);
    sort_k<<<NBKT, 512, 0, stream>>>(tre, scanned, dinv, srn4, rowptr);

    // layer 1
    linear_k<FIN, false><<<NB_LIN, blk, 0, stream>>>(x, W1, tmp8);
    aggregate<<<25000, blk, 0, stream>>>(srn4, rowptr, dinv, b1, tmp8, hA);
    // layer 2
    linear_k<HID, true><<<NB_LIN, blk, 0, stream>>>(hA, W2, tmp8);
    aggregate<<<25000, blk, 0, stream>>>(srn4, rowptr, dinv, b2, tmp8, hB);
    // layer 3
    linear_k<HID, true><<<NB_LIN, blk, 0, stream>>>(hB, W3, tmp8);
    aggregate<<<25000, blk, 0, stream>>>(srn4, rowptr, dinv, b3, tmp8, hA);

    pool_k<<<391, blk, 0, stream>>>(hA, batch, sums, counts);
    mlp_k<<<NG, 64, 0, stream>>>(sums, counts, Wm0, bm0, Wm1, bm1, Wout, bout, out);
}